// Round 13
// baseline (560.539 us; speedup 1.0000x reference)
//
#include <hip/hip_runtime.h>
#include <hip/hip_bf16.h>
#include <cstdint>
#include <cstddef>

#define NN 65536
#define EE 131072
#define GG 4096
#define HH 128
#define DD 64
#define KP 384        // padded input-feature K (321 -> 384)
#define ITEMS 50000

typedef __attribute__((ext_vector_type(8))) short bf16x8;
typedef __attribute__((ext_vector_type(4))) float f32x4;
typedef unsigned short u16;
typedef __attribute__((ext_vector_type(4))) unsigned short u16x4;

#define PINV(x) asm volatile("" : "+v"(x))

__device__ inline void split2(float x, u16* hi, u16* lo) {
    __hip_bfloat16 h = __float2bfloat16(x);
    float hf = __bfloat162float(h);
    __hip_bfloat16 l = __float2bfloat16(x - hf);
    *hi = *reinterpret_cast<u16*>(&h);
    *lo = *reinterpret_cast<u16*>(&l);
}
__device__ inline u16 hi_only(float x) {
    __hip_bfloat16 h = __float2bfloat16(x);
    return *reinterpret_cast<u16*>(&h);
}

// ---------------- embedding gather -> Xhi[N][384] (bf16 hi only) ----------------
__global__ void k_embed(const int* __restrict__ cat, const int* __restrict__ sub,
                        const int* __restrict__ el, const int* __restrict__ br,
                        const int* __restrict__ pid, const float* __restrict__ price,
                        const float* __restrict__ ecat, const float* __restrict__ esub,
                        const float* __restrict__ eel, const float* __restrict__ ebr,
                        const float* __restrict__ eitem, u16* __restrict__ Xhi) {
    int tid = threadIdx.x;
    int n = blockIdx.x * 4 + (tid >> 6);
    int l = tid & 63;
    u16* xh = Xhi + (size_t)n * KP;
    if (l == 0) xh[0] = hi_only(price[n]);
    xh[1 + l]   = hi_only(ecat[(size_t)cat[n] * DD + l]);
    xh[65 + l]  = hi_only(esub[(size_t)sub[n] * DD + l]);
    xh[129 + l] = hi_only(eel [(size_t)el[n]  * DD + l]);
    xh[193 + l] = hi_only(ebr [(size_t)br[n]  * DD + l]);
    xh[257 + l] = hi_only(eitem[(size_t)pid[n]* DD + l]);
    if (l < 63) xh[321 + l] = 0;
}

// ---------------- fp32 -> bf16 hi only ----------------
__global__ void k_cvt_hi(const float* __restrict__ src, u16* __restrict__ hi, int n_total) {
    int i = blockIdx.x * 256 + threadIdx.x;
    if (i >= n_total) return;
    hi[i] = hi_only(src[i]);
}

// ---------------- Wm (128x321) -> hi padded to (128x384) ----------------
__global__ void k_cvt_wm(const float* __restrict__ Wm, u16* __restrict__ hi) {
    int i = blockIdx.x * 256 + threadIdx.x;   // < 128*384
    int r = i / KP, c = i - r * KP;
    float x = (c < 321) ? Wm[r * 321 + c] : 0.f;
    hi[i] = hi_only(x);
}

// ---------------- h = X @ Wm^T + bm  (1-pass MFMA, emits f32 + hi) ----------------
#define M1_STR 132
__launch_bounds__(256, 2)
__global__ void k_mlp1(const u16* __restrict__ Xhi, const u16* __restrict__ Whi,
                       const float* __restrict__ bm, float* __restrict__ h,
                       u16* __restrict__ hhi) {
    __shared__ float ls[128 * M1_STR];
    int tid = threadIdx.x, w = tid >> 6, l = tid & 63;
    int lr = l & 15, lk = l >> 4;
    int m0 = blockIdx.x * 128;
    f32x4 acc[2][8];
    #pragma unroll
    for (int rt = 0; rt < 2; ++rt)
        #pragma unroll
        for (int ci = 0; ci < 8; ++ci) acc[rt][ci] = (f32x4){0.f, 0.f, 0.f, 0.f};

    for (int kc = 0; kc < 12; ++kc) {
        bf16x8 ah[2];
        #pragma unroll
        for (int rt = 0; rt < 2; ++rt) {
            size_t off = (size_t)(m0 + w * 32 + rt * 16 + lr) * KP + kc * 32 + lk * 8;
            ah[rt] = *(const bf16x8*)(Xhi + off);
        }
        #pragma unroll
        for (int ci = 0; ci < 8; ++ci) {
            size_t boff = (size_t)(ci * 16 + lr) * KP + kc * 32 + lk * 8;
            bf16x8 bh = *(const bf16x8*)(Whi + boff);
            #pragma unroll
            for (int rt = 0; rt < 2; ++rt)
                acc[rt][ci] = __builtin_amdgcn_mfma_f32_16x16x32_bf16(ah[rt], bh, acc[rt][ci], 0, 0, 0);
        }
    }
    #pragma unroll
    for (int rt = 0; rt < 2; ++rt)
        #pragma unroll
        for (int ci = 0; ci < 8; ++ci) {
            int col = ci * 16 + lr;
            float bv = bm[col];
            #pragma unroll
            for (int q = 0; q < 4; ++q)
                ls[(w * 32 + rt * 16 + lk * 4 + q) * M1_STR + col] = acc[rt][ci][q] + bv;
        }
    __syncthreads();
    int row = tid >> 1, cb = (tid & 1) * 64;
    float* hd = h + (size_t)(m0 + row) * HH + cb;
    u16* hh = hhi + (size_t)(m0 + row) * HH + cb;
    #pragma unroll
    for (int i = 0; i < 64; i += 4) {
        float4 v = *(const float4*)&ls[row * M1_STR + cb + i];
        *(float4*)(hd + i) = v;
        u16x4 vh;
        vh.x = hi_only(v.x); vh.y = hi_only(v.y);
        vh.z = hi_only(v.z); vh.w = hi_only(v.w);
        *(u16x4*)(hh + i) = vh;
    }
}

// ---------------- edge scatter: msg[dst] += h[src]; cnt[dst] += 1 ----------------
__global__ void k_scatter(const float* __restrict__ h, const int* __restrict__ edge,
                          float* __restrict__ msg, float* __restrict__ cnt) {
    int j = threadIdx.x & 127;
    int eo = threadIdx.x >> 7;
    int e0 = blockIdx.x * 16;
    #pragma unroll
    for (int it = 0; it < 8; ++it) {
        int e = e0 + it * 2 + eo;
        int s = edge[e];
        int d = edge[EE + e];
        atomicAdd(&msg[(size_t)d * HH + j], h[(size_t)s * HH + j]);
        if (j == 0) atomicAdd(&cnt[d], 1.0f);
    }
}

// ---------------- fused GRU: mean + both GEMMs (1-pass) + gates ----------------
#define GRU_STR 136
__launch_bounds__(256, 2)
__global__ void k_gru(const float* __restrict__ msg, const float* __restrict__ cnt,
                      const u16* __restrict__ hhi_in,
                      const u16* __restrict__ Wihh, const u16* __restrict__ Whhh,
                      const float* __restrict__ b_ih, const float* __restrict__ b_hh,
                      float* __restrict__ h, u16* __restrict__ hhi) {
    __shared__ float ls[32 * GRU_STR];
    int tid = threadIdx.x, w = tid >> 6, l = tid & 63;
    int lr = l & 15, lk = l >> 4;
    int m0 = blockIdx.x * 32;
    f32x4 acc[6][2][2];
    #pragma unroll
    for (int g = 0; g < 6; ++g)
        #pragma unroll
        for (int ct = 0; ct < 2; ++ct)
            #pragma unroll
            for (int rt = 0; rt < 2; ++rt) acc[g][ct][rt] = (f32x4){0.f, 0.f, 0.f, 0.f};

    float cinv[2];
    const float* mrow[2];
    #pragma unroll
    for (int rt = 0; rt < 2; ++rt) {
        int row = m0 + rt * 16 + lr;
        cinv[rt] = 1.0f / fmaxf(cnt[row], 1.0f);
        mrow[rt] = msg + (size_t)row * HH + lk * 8;
    }

    for (int kc = 0; kc < 4; ++kc) {
        bf16x8 amh[2], ahh[2];
        #pragma unroll
        for (int rt = 0; rt < 2; ++rt) {
            float4 v0 = *(const float4*)(mrow[rt] + kc * 32);
            float4 v1 = *(const float4*)(mrow[rt] + kc * 32 + 4);
            float xs[8] = {v0.x * cinv[rt], v0.y * cinv[rt], v0.z * cinv[rt], v0.w * cinv[rt],
                           v1.x * cinv[rt], v1.y * cinv[rt], v1.z * cinv[rt], v1.w * cinv[rt]};
            #pragma unroll
            for (int q = 0; q < 8; ++q) amh[rt][q] = (short)hi_only(xs[q]);
            size_t off = (size_t)(m0 + rt * 16 + lr) * HH + kc * 32 + lk * 8;
            ahh[rt] = *(const bf16x8*)(hhi_in + off);
        }
        #pragma unroll
        for (int g = 0; g < 6; ++g) {
            const u16* WH = (g < 3) ? Wihh : Whhh;
            int gb = (g % 3) * HH;
            #pragma unroll
            for (int ct = 0; ct < 2; ++ct) {
                size_t boff = (size_t)(gb + w * 32 + ct * 16 + lr) * HH + kc * 32 + lk * 8;
                bf16x8 bh = *(const bf16x8*)(WH + boff);
                #pragma unroll
                for (int rt = 0; rt < 2; ++rt) {
                    bf16x8 ah = (g < 3) ? amh[rt] : ahh[rt];
                    acc[g][ct][rt] = __builtin_amdgcn_mfma_f32_16x16x32_bf16(ah, bh, acc[g][ct][rt], 0, 0, 0);
                }
            }
        }
    }
    #pragma unroll
    for (int ct = 0; ct < 2; ++ct) {
        int col = w * 32 + ct * 16 + lr;
        float bir = b_ih[col], biz = b_ih[HH + col], bin = b_ih[2 * HH + col];
        float bhr = b_hh[col], bhz = b_hh[HH + col], bhn = b_hh[2 * HH + col];
        #pragma unroll
        for (int rt = 0; rt < 2; ++rt)
            #pragma unroll
            for (int q = 0; q < 4; ++q) {
                int rl = rt * 16 + lk * 4 + q;
                float gir = acc[0][ct][rt][q] + bir;
                float giz = acc[1][ct][rt][q] + biz;
                float gin = acc[2][ct][rt][q] + bin;
                float ghr = acc[3][ct][rt][q] + bhr;
                float ghz = acc[4][ct][rt][q] + bhz;
                float ghn = acc[5][ct][rt][q] + bhn;
                float hv = h[(size_t)(m0 + rl) * HH + col];
                float r = 1.f / (1.f + expf(-(gir + ghr)));
                float z = 1.f / (1.f + expf(-(giz + ghz)));
                float nn = tanhf(gin + r * ghn);
                ls[rl * GRU_STR + col] = (1.f - z) * nn + z * hv;
            }
    }
    __syncthreads();
    int row = tid >> 3, cb = (tid & 7) * 16;
    float* hd = h + (size_t)(m0 + row) * HH + cb;
    u16* hh = hhi + (size_t)(m0 + row) * HH + cb;
    #pragma unroll
    for (int i = 0; i < 16; i += 4) {
        float4 v = *(const float4*)&ls[row * GRU_STR + cb + i];
        *(float4*)(hd + i) = v;
        u16x4 vh;
        vh.x = hi_only(v.x); vh.y = hi_only(v.y);
        vh.z = hi_only(v.z); vh.w = hi_only(v.w);
        *(u16x4*)(hh + i) = vh;
    }
}

// ---------------- fused gate + segment-softmax + pool + split ----------------
__launch_bounds__(256, 2)
__global__ void k_gatepool(const u16* __restrict__ hhi, const float* __restrict__ h,
                           const u16* __restrict__ Ghi, const float* __restrict__ bg1,
                           const float* __restrict__ Wg2,
                           u16* __restrict__ phi, u16* __restrict__ plo) {
    __shared__ float sal[128];
    int tid = threadIdx.x, w = tid >> 6, l = tid & 63;
    int lr = l & 15, lk = l >> 4;
    int m0 = blockIdx.x * 128;
    f32x4 acc[2][8];
    #pragma unroll
    for (int rt = 0; rt < 2; ++rt)
        #pragma unroll
        for (int ci = 0; ci < 8; ++ci) acc[rt][ci] = (f32x4){0.f, 0.f, 0.f, 0.f};

    for (int kc = 0; kc < 4; ++kc) {
        bf16x8 ah[2];
        #pragma unroll
        for (int rt = 0; rt < 2; ++rt) {
            size_t off = (size_t)(m0 + w * 32 + rt * 16 + lr) * HH + kc * 32 + lk * 8;
            ah[rt] = *(const bf16x8*)(hhi + off);
        }
        #pragma unroll
        for (int ci = 0; ci < 8; ++ci) {
            size_t boff = (size_t)(ci * 16 + lr) * HH + kc * 32 + lk * 8;
            bf16x8 bh = *(const bf16x8*)(Ghi + boff);
            #pragma unroll
            for (int rt = 0; rt < 2; ++rt)
                acc[rt][ci] = __builtin_amdgcn_mfma_f32_16x16x32_bf16(ah[rt], bh, acc[rt][ci], 0, 0, 0);
        }
    }
    float part[2][4] = {};
    #pragma unroll
    for (int ci = 0; ci < 8; ++ci) {
        int col = ci * 16 + lr;
        float wv = Wg2[col], bb = bg1[col];
        #pragma unroll
        for (int rt = 0; rt < 2; ++rt)
            #pragma unroll
            for (int q = 0; q < 4; ++q)
                part[rt][q] += fmaxf(acc[rt][ci][q] + bb, 0.f) * wv;
    }
    #pragma unroll
    for (int rt = 0; rt < 2; ++rt)
        #pragma unroll
        for (int q = 0; q < 4; ++q) {
            float v = part[rt][q];
            v += __shfl_xor(v, 1);
            v += __shfl_xor(v, 2);
            v += __shfl_xor(v, 4);
            v += __shfl_xor(v, 8);
            part[rt][q] = v;
        }
    if (lr == 0) {
        #pragma unroll
        for (int rt = 0; rt < 2; ++rt)
            #pragma unroll
            for (int q = 0; q < 4; ++q)
                sal[w * 32 + rt * 16 + lk * 4 + q] = part[rt][q];
    }
    __syncthreads();

    int g2 = tid >> 5;
    int c = (tid & 31) * 4;
    int rb = g2 * 16;
    float gv[16];
    float mx = -1e30f;
    #pragma unroll
    for (int i = 0; i < 16; ++i) { gv[i] = sal[rb + i]; mx = fmaxf(mx, gv[i]); }
    float den = 0.f;
    #pragma unroll
    for (int i = 0; i < 16; ++i) { gv[i] = expf(gv[i] - mx); den += gv[i]; }
    float inv = 1.f / den;
    f32x4 a = (f32x4){0.f, 0.f, 0.f, 0.f};
    #pragma unroll
    for (int i = 0; i < 16; ++i) {
        float4 hv = *(const float4*)&h[(size_t)(m0 + rb + i) * HH + c];
        float wgt = gv[i] * inv;
        a[0] += wgt * hv.x; a[1] += wgt * hv.y; a[2] += wgt * hv.z; a[3] += wgt * hv.w;
    }
    size_t po = (size_t)(blockIdx.x * 8 + g2) * HH + c;
    u16x4 vh, vl;
    #pragma unroll
    for (int q = 0; q < 4; ++q) split2(a[q], (u16*)&vh + q, (u16*)&vl + q);
    *(u16x4*)(phi + po) = vh;
    *(u16x4*)(plo + po) = vl;
}

// ---------------- FC v10: 1024-col strips, 8 waves, 4KB/row contiguous stores ----------------
// grid (49, 16) x-fastest: ~256 resident blocks cover whole row-regions together.
// Wave w owns cols [c0+w*128, +128) as 8 col-tiles; W-hi fragments 128 VGPR,
// pinned. A = pooled hi+lo (2-pass, accuracy-critical final GEMM). 16-row tiles,
// LDS dbuf (132KB, 1 block/CU, 8 waves). FLUSH: wave w writes rows {2w,2w+1},
// 4 x 1KB nt stores each -> 4KB/row/block. lgkm-only barrier.
#define FC10_STR 1032
__launch_bounds__(512, 1)
__global__ void k_fc10(const float* __restrict__ Wfc,
                       const u16* __restrict__ phi, const u16* __restrict__ plo,
                       const float* __restrict__ bfc, float* __restrict__ out) {
    __shared__ float ls[2][16][FC10_STR];
    int tid = threadIdx.x, w = tid >> 6, l = tid & 63;
    int lr = l & 15, lk = l >> 4;
    int c0 = blockIdx.x * 1024;
    int mbase = blockIdx.y * 256;

    bf16x8 bh[8][4];
    float bias[8];
    #pragma unroll
    for (int ci = 0; ci < 8; ++ci) {
        int n = c0 + w * 128 + ci * 16 + lr;
        bool ok = (n < ITEMS);
        const float* Wr = Wfc + (size_t)n * HH;
        #pragma unroll
        for (int kc = 0; kc < 4; ++kc) {
            float4 v0 = ok ? *(const float4*)(Wr + kc * 32 + lk * 8)     : make_float4(0.f,0.f,0.f,0.f);
            float4 v1 = ok ? *(const float4*)(Wr + kc * 32 + lk * 8 + 4) : make_float4(0.f,0.f,0.f,0.f);
            float xs[8] = {v0.x, v0.y, v0.z, v0.w, v1.x, v1.y, v1.z, v1.w};
            bf16x8 hv;
            #pragma unroll
            for (int q = 0; q < 8; ++q) hv[q] = (short)hi_only(xs[q]);
            bh[ci][kc] = hv;
        }
        bias[ci] = ok ? bfc[n] : 0.f;
    }
    #pragma unroll
    for (int ci = 0; ci < 8; ++ci)
        #pragma unroll
        for (int kc = 0; kc < 4; ++kc) PINV(bh[ci][kc]);

    bf16x8 a0h[4], a0l[4], a1h[4], a1l[4];
    auto LOADA = [&](int t, bf16x8* Ah, bf16x8* Al) {
        int m0 = mbase + t * 16;
        size_t aoff = (size_t)(m0 + lr) * HH + lk * 8;
        #pragma unroll
        for (int kc = 0; kc < 4; ++kc) {
            Ah[kc] = *(const bf16x8*)(phi + aoff + kc * 32);
            Al[kc] = *(const bf16x8*)(plo + aoff + kc * 32);
        }
    };
    auto COMP = [&](const bf16x8* Ah, const bf16x8* Al, int b) {
        #pragma unroll
        for (int ci = 0; ci < 8; ++ci) {
            f32x4 acc = (f32x4){0.f, 0.f, 0.f, 0.f};
            #pragma unroll
            for (int kc = 0; kc < 4; ++kc) {
                acc = __builtin_amdgcn_mfma_f32_16x16x32_bf16(Ah[kc], bh[ci][kc], acc, 0, 0, 0);
                acc = __builtin_amdgcn_mfma_f32_16x16x32_bf16(Al[kc], bh[ci][kc], acc, 0, 0, 0);
            }
            #pragma unroll
            for (int q = 0; q < 4; ++q)
                ls[b][lk * 4 + q][w * 128 + ci * 16 + lr] = acc[q] + bias[ci];
        }
    };
    auto FLUSH = [&](int t, int b) {
        int m0 = mbase + t * 16;
        #pragma unroll
        for (int p = 0; p < 2; ++p) {
            int row = w * 2 + p;
            #pragma unroll
            for (int s = 0; s < 4; ++s) {
                int c = s * 256 + l * 4;
                int gc = c0 + c;
                if (gc < ITEMS) {
                    f32x4 v = *(const f32x4*)&ls[b][row][c];
                    __builtin_nontemporal_store(v, (f32x4*)&out[(size_t)(m0 + row) * ITEMS + gc]);
                }
            }
        }
    };
    auto softbar = [&]() {
        asm volatile("s_waitcnt lgkmcnt(0)" ::: "memory");
        __builtin_amdgcn_s_barrier();
    };

    LOADA(0, a0h, a0l);
    LOADA(1, a1h, a1l);
    COMP(a0h, a0l, 0);
    softbar();
    for (int t = 1; t < 16; ++t) {
        if (t + 1 < 16) {
            if ((t + 1) & 1) LOADA(t + 1, a1h, a1l);
            else             LOADA(t + 1, a0h, a0l);
        }
        if (t & 1) COMP(a1h, a1l, 1);
        else       COMP(a0h, a0l, 0);
        FLUSH(t - 1, (t - 1) & 1);
        softbar();
    }
    FLUSH(15, 1);
}

extern "C" void kernel_launch(void* const* d_in, const int* in_sizes, int n_in,
                              void* d_out, int out_size, void* d_ws, size_t ws_size,
                              hipStream_t stream) {
    const int* category = (const int*)d_in[0];
    const int* sub_cat  = (const int*)d_in[1];
    const int* element  = (const int*)d_in[2];
    const int* brand    = (const int*)d_in[3];
    const int* pid      = (const int*)d_in[4];
    const float* price  = (const float*)d_in[5];
    const int* edge     = (const int*)d_in[6];
    const float* ecat   = (const float*)d_in[8];
    const float* esub   = (const float*)d_in[9];
    const float* eel    = (const float*)d_in[10];
    const float* ebr    = (const float*)d_in[11];
    const float* eitem  = (const float*)d_in[12];
    const float* Wm     = (const float*)d_in[13];
    const float* bm     = (const float*)d_in[14];
    const float* W_ih   = (const float*)d_in[15];
    const float* b_ih   = (const float*)d_in[16];
    const float* W_hh   = (const float*)d_in[17];
    const float* b_hh   = (const float*)d_in[18];
    const float* Wg1    = (const float*)d_in[19];
    const float* bg1    = (const float*)d_in[20];
    const float* Wg2    = (const float*)d_in[21];
    // d_in[22] = bg2 (cancels in softmax)
    const float* Wfc    = (const float*)d_in[23];
    const float* bfc    = (const float*)d_in[24];
    float* out = (float*)d_out;

    // ---- workspace carve-up (bytes), 256B-aligned regions ----
    char* p = (char*)d_ws;
    auto alloc = [&](size_t bytes) { char* r = p; p += (bytes + 255) & ~(size_t)255; return r; };
    u16* Xhi   = (u16*)alloc((size_t)NN * KP * 2);
    float* h   = (float*)alloc((size_t)NN * HH * 4);
    u16* hhi   = (u16*)alloc((size_t)NN * HH * 2);
    float* msg = (float*)alloc((size_t)NN * HH * 4);
    float* cnt = (float*)alloc((size_t)NN * 4);
    u16* phi   = (u16*)alloc((size_t)GG * HH * 2);
    u16* plo   = (u16*)alloc((size_t)GG * HH * 2);
    u16* Wmhi  = (u16*)alloc((size_t)HH * KP * 2);
    u16* Wihhi = (u16*)alloc((size_t)3 * HH * HH * 2);
    u16* Whhhi = (u16*)alloc((size_t)3 * HH * HH * 2);
    u16* Wg1hi = (u16*)alloc((size_t)HH * HH * 2);

    hipMemsetAsync(msg, 0, (size_t)NN * HH * sizeof(float), stream);
    hipMemsetAsync(cnt, 0, (size_t)NN * sizeof(float), stream);

    // weight conversions (hi-only)
    k_cvt_wm<<<(HH * KP + 255) / 256, 256, 0, stream>>>(Wm, Wmhi);
    k_cvt_hi<<<(3 * HH * HH + 255) / 256, 256, 0, stream>>>(W_ih, Wihhi, 3 * HH * HH);
    k_cvt_hi<<<(3 * HH * HH + 255) / 256, 256, 0, stream>>>(W_hh, Whhhi, 3 * HH * HH);
    k_cvt_hi<<<(HH * HH + 255) / 256, 256, 0, stream>>>(Wg1, Wg1hi, HH * HH);

    // 1. embedding gather -> X hi
    k_embed<<<NN / 4, 256, 0, stream>>>(category, sub_cat, element, brand, pid, price,
                                        ecat, esub, eel, ebr, eitem, Xhi);
    // 2. h = X @ Wm^T + bm
    k_mlp1<<<NN / 128, 256, 0, stream>>>(Xhi, Wmhi, bm, h, hhi);
    // 3. scatter (mean fused into k_gru)
    k_scatter<<<EE / 16, 256, 0, stream>>>(h, edge, msg, cnt);
    // 4. fused GRU (updates h, hhi in place)
    k_gru<<<NN / 32, 256, 0, stream>>>(msg, cnt, hhi, Wihhi, Whhhi,
                                       b_ih, b_hh, h, hhi);
    // 5. fused gate + softmax + pool -> pooled pair
    k_gatepool<<<NN / 128, 256, 0, stream>>>(hhi, h, Wg1hi, bg1, Wg2, phi, plo);
    // 6. out = pooled @ Wfc^T + bfc
    k_fc10<<<dim3(49, 16), 512, 0, stream>>>(Wfc, phi, plo, bfc, out);
}

// Round 14
// 448.815 us; speedup vs baseline: 1.2489x; 1.2489x over previous
//
#include <hip/hip_runtime.h>
#include <hip/hip_bf16.h>
#include <cstdint>
#include <cstddef>

#define NN 65536
#define EE 131072
#define GG 4096
#define HH 128
#define DD 64
#define KP 384        // padded input-feature K (321 -> 384)
#define ITEMS 50000

typedef __attribute__((ext_vector_type(8))) short bf16x8;
typedef __attribute__((ext_vector_type(4))) float f32x4;
typedef unsigned short u16;
typedef __attribute__((ext_vector_type(4))) unsigned short u16x4;

#define PINV(x) asm volatile("" : "+v"(x))

__device__ inline void split2(float x, u16* hi, u16* lo) {
    __hip_bfloat16 h = __float2bfloat16(x);
    float hf = __bfloat162float(h);
    __hip_bfloat16 l = __float2bfloat16(x - hf);
    *hi = *reinterpret_cast<u16*>(&h);
    *lo = *reinterpret_cast<u16*>(&l);
}
__device__ inline u16 hi_only(float x) {
    __hip_bfloat16 h = __float2bfloat16(x);
    return *reinterpret_cast<u16*>(&h);
}

// ---------------- embedding gather -> Xhi[N][384] (bf16 hi only) ----------------
__global__ void k_embed(const int* __restrict__ cat, const int* __restrict__ sub,
                        const int* __restrict__ el, const int* __restrict__ br,
                        const int* __restrict__ pid, const float* __restrict__ price,
                        const float* __restrict__ ecat, const float* __restrict__ esub,
                        const float* __restrict__ eel, const float* __restrict__ ebr,
                        const float* __restrict__ eitem, u16* __restrict__ Xhi) {
    int tid = threadIdx.x;
    int n = blockIdx.x * 4 + (tid >> 6);
    int l = tid & 63;
    u16* xh = Xhi + (size_t)n * KP;
    if (l == 0) xh[0] = hi_only(price[n]);
    xh[1 + l]   = hi_only(ecat[(size_t)cat[n] * DD + l]);
    xh[65 + l]  = hi_only(esub[(size_t)sub[n] * DD + l]);
    xh[129 + l] = hi_only(eel [(size_t)el[n]  * DD + l]);
    xh[193 + l] = hi_only(ebr [(size_t)br[n]  * DD + l]);
    xh[257 + l] = hi_only(eitem[(size_t)pid[n]* DD + l]);
    if (l < 63) xh[321 + l] = 0;
}

// ---------------- fp32 -> bf16 hi only ----------------
__global__ void k_cvt_hi(const float* __restrict__ src, u16* __restrict__ hi, int n_total) {
    int i = blockIdx.x * 256 + threadIdx.x;
    if (i >= n_total) return;
    hi[i] = hi_only(src[i]);
}

// ---------------- Wm (128x321) -> hi padded to (128x384) ----------------
__global__ void k_cvt_wm(const float* __restrict__ Wm, u16* __restrict__ hi) {
    int i = blockIdx.x * 256 + threadIdx.x;   // < 128*384
    int r = i / KP, c = i - r * KP;
    float x = (c < 321) ? Wm[r * 321 + c] : 0.f;
    hi[i] = hi_only(x);
}

// ---------------- h = X @ Wm^T + bm  (1-pass MFMA, emits f32 + hi) ----------------
#define M1_STR 132
__launch_bounds__(256, 2)
__global__ void k_mlp1(const u16* __restrict__ Xhi, const u16* __restrict__ Whi,
                       const float* __restrict__ bm, float* __restrict__ h,
                       u16* __restrict__ hhi) {
    __shared__ float ls[128 * M1_STR];
    int tid = threadIdx.x, w = tid >> 6, l = tid & 63;
    int lr = l & 15, lk = l >> 4;
    int m0 = blockIdx.x * 128;
    f32x4 acc[2][8];
    #pragma unroll
    for (int rt = 0; rt < 2; ++rt)
        #pragma unroll
        for (int ci = 0; ci < 8; ++ci) acc[rt][ci] = (f32x4){0.f, 0.f, 0.f, 0.f};

    for (int kc = 0; kc < 12; ++kc) {
        bf16x8 ah[2];
        #pragma unroll
        for (int rt = 0; rt < 2; ++rt) {
            size_t off = (size_t)(m0 + w * 32 + rt * 16 + lr) * KP + kc * 32 + lk * 8;
            ah[rt] = *(const bf16x8*)(Xhi + off);
        }
        #pragma unroll
        for (int ci = 0; ci < 8; ++ci) {
            size_t boff = (size_t)(ci * 16 + lr) * KP + kc * 32 + lk * 8;
            bf16x8 bh = *(const bf16x8*)(Whi + boff);
            #pragma unroll
            for (int rt = 0; rt < 2; ++rt)
                acc[rt][ci] = __builtin_amdgcn_mfma_f32_16x16x32_bf16(ah[rt], bh, acc[rt][ci], 0, 0, 0);
        }
    }
    #pragma unroll
    for (int rt = 0; rt < 2; ++rt)
        #pragma unroll
        for (int ci = 0; ci < 8; ++ci) {
            int col = ci * 16 + lr;
            float bv = bm[col];
            #pragma unroll
            for (int q = 0; q < 4; ++q)
                ls[(w * 32 + rt * 16 + lk * 4 + q) * M1_STR + col] = acc[rt][ci][q] + bv;
        }
    __syncthreads();
    int row = tid >> 1, cb = (tid & 1) * 64;
    float* hd = h + (size_t)(m0 + row) * HH + cb;
    u16* hh = hhi + (size_t)(m0 + row) * HH + cb;
    #pragma unroll
    for (int i = 0; i < 64; i += 4) {
        float4 v = *(const float4*)&ls[row * M1_STR + cb + i];
        *(float4*)(hd + i) = v;
        u16x4 vh;
        vh.x = hi_only(v.x); vh.y = hi_only(v.y);
        vh.z = hi_only(v.z); vh.w = hi_only(v.w);
        *(u16x4*)(hh + i) = vh;
    }
}

// ---------------- edge scatter: msg[dst] += h[src]; cnt[dst] += 1 ----------------
__global__ void k_scatter(const float* __restrict__ h, const int* __restrict__ edge,
                          float* __restrict__ msg, float* __restrict__ cnt) {
    int j = threadIdx.x & 127;
    int eo = threadIdx.x >> 7;
    int e0 = blockIdx.x * 16;
    #pragma unroll
    for (int it = 0; it < 8; ++it) {
        int e = e0 + it * 2 + eo;
        int s = edge[e];
        int d = edge[EE + e];
        atomicAdd(&msg[(size_t)d * HH + j], h[(size_t)s * HH + j]);
        if (j == 0) atomicAdd(&cnt[d], 1.0f);
    }
}

// ---------------- fused GRU: mean + both GEMMs (1-pass) + gates ----------------
#define GRU_STR 136
__launch_bounds__(256, 2)
__global__ void k_gru(const float* __restrict__ msg, const float* __restrict__ cnt,
                      const u16* __restrict__ hhi_in,
                      const u16* __restrict__ Wihh, const u16* __restrict__ Whhh,
                      const float* __restrict__ b_ih, const float* __restrict__ b_hh,
                      float* __restrict__ h, u16* __restrict__ hhi) {
    __shared__ float ls[32 * GRU_STR];
    int tid = threadIdx.x, w = tid >> 6, l = tid & 63;
    int lr = l & 15, lk = l >> 4;
    int m0 = blockIdx.x * 32;
    f32x4 acc[6][2][2];
    #pragma unroll
    for (int g = 0; g < 6; ++g)
        #pragma unroll
        for (int ct = 0; ct < 2; ++ct)
            #pragma unroll
            for (int rt = 0; rt < 2; ++rt) acc[g][ct][rt] = (f32x4){0.f, 0.f, 0.f, 0.f};

    float cinv[2];
    const float* mrow[2];
    #pragma unroll
    for (int rt = 0; rt < 2; ++rt) {
        int row = m0 + rt * 16 + lr;
        cinv[rt] = 1.0f / fmaxf(cnt[row], 1.0f);
        mrow[rt] = msg + (size_t)row * HH + lk * 8;
    }

    for (int kc = 0; kc < 4; ++kc) {
        bf16x8 amh[2], ahh[2];
        #pragma unroll
        for (int rt = 0; rt < 2; ++rt) {
            float4 v0 = *(const float4*)(mrow[rt] + kc * 32);
            float4 v1 = *(const float4*)(mrow[rt] + kc * 32 + 4);
            float xs[8] = {v0.x * cinv[rt], v0.y * cinv[rt], v0.z * cinv[rt], v0.w * cinv[rt],
                           v1.x * cinv[rt], v1.y * cinv[rt], v1.z * cinv[rt], v1.w * cinv[rt]};
            #pragma unroll
            for (int q = 0; q < 8; ++q) amh[rt][q] = (short)hi_only(xs[q]);
            size_t off = (size_t)(m0 + rt * 16 + lr) * HH + kc * 32 + lk * 8;
            ahh[rt] = *(const bf16x8*)(hhi_in + off);
        }
        #pragma unroll
        for (int g = 0; g < 6; ++g) {
            const u16* WH = (g < 3) ? Wihh : Whhh;
            int gb = (g % 3) * HH;
            #pragma unroll
            for (int ct = 0; ct < 2; ++ct) {
                size_t boff = (size_t)(gb + w * 32 + ct * 16 + lr) * HH + kc * 32 + lk * 8;
                bf16x8 bh = *(const bf16x8*)(WH + boff);
                #pragma unroll
                for (int rt = 0; rt < 2; ++rt) {
                    bf16x8 ah = (g < 3) ? amh[rt] : ahh[rt];
                    acc[g][ct][rt] = __builtin_amdgcn_mfma_f32_16x16x32_bf16(ah, bh, acc[g][ct][rt], 0, 0, 0);
                }
            }
        }
    }
    #pragma unroll
    for (int ct = 0; ct < 2; ++ct) {
        int col = w * 32 + ct * 16 + lr;
        float bir = b_ih[col], biz = b_ih[HH + col], bin = b_ih[2 * HH + col];
        float bhr = b_hh[col], bhz = b_hh[HH + col], bhn = b_hh[2 * HH + col];
        #pragma unroll
        for (int rt = 0; rt < 2; ++rt)
            #pragma unroll
            for (int q = 0; q < 4; ++q) {
                int rl = rt * 16 + lk * 4 + q;
                float gir = acc[0][ct][rt][q] + bir;
                float giz = acc[1][ct][rt][q] + biz;
                float gin = acc[2][ct][rt][q] + bin;
                float ghr = acc[3][ct][rt][q] + bhr;
                float ghz = acc[4][ct][rt][q] + bhz;
                float ghn = acc[5][ct][rt][q] + bhn;
                float hv = h[(size_t)(m0 + rl) * HH + col];
                float r = 1.f / (1.f + expf(-(gir + ghr)));
                float z = 1.f / (1.f + expf(-(giz + ghz)));
                float nn = tanhf(gin + r * ghn);
                ls[rl * GRU_STR + col] = (1.f - z) * nn + z * hv;
            }
    }
    __syncthreads();
    int row = tid >> 3, cb = (tid & 7) * 16;
    float* hd = h + (size_t)(m0 + row) * HH + cb;
    u16* hh = hhi + (size_t)(m0 + row) * HH + cb;
    #pragma unroll
    for (int i = 0; i < 16; i += 4) {
        float4 v = *(const float4*)&ls[row * GRU_STR + cb + i];
        *(float4*)(hd + i) = v;
        u16x4 vh;
        vh.x = hi_only(v.x); vh.y = hi_only(v.y);
        vh.z = hi_only(v.z); vh.w = hi_only(v.w);
        *(u16x4*)(hh + i) = vh;
    }
}

// ---------------- fused gate + segment-softmax + pool + split ----------------
__launch_bounds__(256, 2)
__global__ void k_gatepool(const u16* __restrict__ hhi, const float* __restrict__ h,
                           const u16* __restrict__ Ghi, const float* __restrict__ bg1,
                           const float* __restrict__ Wg2,
                           u16* __restrict__ phi, u16* __restrict__ plo) {
    __shared__ float sal[128];
    int tid = threadIdx.x, w = tid >> 6, l = tid & 63;
    int lr = l & 15, lk = l >> 4;
    int m0 = blockIdx.x * 128;
    f32x4 acc[2][8];
    #pragma unroll
    for (int rt = 0; rt < 2; ++rt)
        #pragma unroll
        for (int ci = 0; ci < 8; ++ci) acc[rt][ci] = (f32x4){0.f, 0.f, 0.f, 0.f};

    for (int kc = 0; kc < 4; ++kc) {
        bf16x8 ah[2];
        #pragma unroll
        for (int rt = 0; rt < 2; ++rt) {
            size_t off = (size_t)(m0 + w * 32 + rt * 16 + lr) * HH + kc * 32 + lk * 8;
            ah[rt] = *(const bf16x8*)(hhi + off);
        }
        #pragma unroll
        for (int ci = 0; ci < 8; ++ci) {
            size_t boff = (size_t)(ci * 16 + lr) * HH + kc * 32 + lk * 8;
            bf16x8 bh = *(const bf16x8*)(Ghi + boff);
            #pragma unroll
            for (int rt = 0; rt < 2; ++rt)
                acc[rt][ci] = __builtin_amdgcn_mfma_f32_16x16x32_bf16(ah[rt], bh, acc[rt][ci], 0, 0, 0);
        }
    }
    float part[2][4] = {};
    #pragma unroll
    for (int ci = 0; ci < 8; ++ci) {
        int col = ci * 16 + lr;
        float wv = Wg2[col], bb = bg1[col];
        #pragma unroll
        for (int rt = 0; rt < 2; ++rt)
            #pragma unroll
            for (int q = 0; q < 4; ++q)
                part[rt][q] += fmaxf(acc[rt][ci][q] + bb, 0.f) * wv;
    }
    #pragma unroll
    for (int rt = 0; rt < 2; ++rt)
        #pragma unroll
        for (int q = 0; q < 4; ++q) {
            float v = part[rt][q];
            v += __shfl_xor(v, 1);
            v += __shfl_xor(v, 2);
            v += __shfl_xor(v, 4);
            v += __shfl_xor(v, 8);
            part[rt][q] = v;
        }
    if (lr == 0) {
        #pragma unroll
        for (int rt = 0; rt < 2; ++rt)
            #pragma unroll
            for (int q = 0; q < 4; ++q)
                sal[w * 32 + rt * 16 + lk * 4 + q] = part[rt][q];
    }
    __syncthreads();

    int g2 = tid >> 5;
    int c = (tid & 31) * 4;
    int rb = g2 * 16;
    float gv[16];
    float mx = -1e30f;
    #pragma unroll
    for (int i = 0; i < 16; ++i) { gv[i] = sal[rb + i]; mx = fmaxf(mx, gv[i]); }
    float den = 0.f;
    #pragma unroll
    for (int i = 0; i < 16; ++i) { gv[i] = expf(gv[i] - mx); den += gv[i]; }
    float inv = 1.f / den;
    f32x4 a = (f32x4){0.f, 0.f, 0.f, 0.f};
    #pragma unroll
    for (int i = 0; i < 16; ++i) {
        float4 hv = *(const float4*)&h[(size_t)(m0 + rb + i) * HH + c];
        float wgt = gv[i] * inv;
        a[0] += wgt * hv.x; a[1] += wgt * hv.y; a[2] += wgt * hv.z; a[3] += wgt * hv.w;
    }
    size_t po = (size_t)(blockIdx.x * 8 + g2) * HH + c;
    u16x4 vh, vl;
    #pragma unroll
    for (int q = 0; q < 4; ++q) split2(a[q], (u16*)&vh + q, (u16*)&vl + q);
    *(u16x4*)(phi + po) = vh;
    *(u16x4*)(plo + po) = vl;
}

// ---------------- FC v11: fc8 structure (256thr/2 blocks per CU), y=4 ----------------
// grid (98, 4): 392 blocks, each sweeps 1024 rows (64 x 16-row tiles) of its
// 512-col strip -> halves Wfc refetch vs (98,8). Wave w owns cols
// [c0+w*128,+128) as 8 col-tiles; W-hi fragments 128 VGPR, pinned.
// A = pooled hi+lo (2-pass). LDS dbuf 66KB; 2-deep A prefetch; lgkm-only
// barrier; nt stores; 2KB/row per block FLUSH.
#define FC_STR 520
__launch_bounds__(256, 2)
__global__ void k_fc11(const float* __restrict__ Wfc,
                       const u16* __restrict__ phi, const u16* __restrict__ plo,
                       const float* __restrict__ bfc, float* __restrict__ out) {
    __shared__ float ls[2][16][FC_STR];
    int tid = threadIdx.x, w = tid >> 6, l = tid & 63;
    int lr = l & 15, lk = l >> 4;
    int c0 = blockIdx.x * 512;
    int mbase = blockIdx.y * 1024;

    bf16x8 bh[8][4];
    float bias[8];
    #pragma unroll
    for (int ci = 0; ci < 8; ++ci) {
        int n = c0 + w * 128 + ci * 16 + lr;
        bool ok = (n < ITEMS);
        const float* Wr = Wfc + (size_t)n * HH;
        #pragma unroll
        for (int kc = 0; kc < 4; ++kc) {
            float4 v0 = ok ? *(const float4*)(Wr + kc * 32 + lk * 8)     : make_float4(0.f,0.f,0.f,0.f);
            float4 v1 = ok ? *(const float4*)(Wr + kc * 32 + lk * 8 + 4) : make_float4(0.f,0.f,0.f,0.f);
            float xs[8] = {v0.x, v0.y, v0.z, v0.w, v1.x, v1.y, v1.z, v1.w};
            bf16x8 hv;
            #pragma unroll
            for (int q = 0; q < 8; ++q) hv[q] = (short)hi_only(xs[q]);
            bh[ci][kc] = hv;
        }
        bias[ci] = ok ? bfc[n] : 0.f;
    }
    #pragma unroll
    for (int ci = 0; ci < 8; ++ci)
        #pragma unroll
        for (int kc = 0; kc < 4; ++kc) PINV(bh[ci][kc]);

    bf16x8 a0h[4], a0l[4], a1h[4], a1l[4];
    auto LOADA = [&](int t, bf16x8* Ah, bf16x8* Al) {
        int m0 = mbase + t * 16;
        size_t aoff = (size_t)(m0 + lr) * HH + lk * 8;
        #pragma unroll
        for (int kc = 0; kc < 4; ++kc) {
            Ah[kc] = *(const bf16x8*)(phi + aoff + kc * 32);
            Al[kc] = *(const bf16x8*)(plo + aoff + kc * 32);
        }
    };
    auto COMP = [&](const bf16x8* Ah, const bf16x8* Al, int b) {
        #pragma unroll
        for (int ci = 0; ci < 8; ++ci) {
            f32x4 acc = (f32x4){0.f, 0.f, 0.f, 0.f};
            #pragma unroll
            for (int kc = 0; kc < 4; ++kc) {
                acc = __builtin_amdgcn_mfma_f32_16x16x32_bf16(Ah[kc], bh[ci][kc], acc, 0, 0, 0);
                acc = __builtin_amdgcn_mfma_f32_16x16x32_bf16(Al[kc], bh[ci][kc], acc, 0, 0, 0);
            }
            #pragma unroll
            for (int q = 0; q < 4; ++q)
                ls[b][lk * 4 + q][w * 128 + ci * 16 + lr] = acc[q] + bias[ci];
        }
    };
    auto FLUSH = [&](int t, int b) {
        int m0 = mbase + t * 16;
        #pragma unroll
        for (int p = 0; p < 4; ++p) {
            int row = w * 4 + p;
            #pragma unroll
            for (int s = 0; s < 2; ++s) {
                int c = s * 256 + l * 4;
                int gc = c0 + c;
                if (gc < ITEMS) {
                    f32x4 v = *(const f32x4*)&ls[b][row][c];
                    __builtin_nontemporal_store(v, (f32x4*)&out[(size_t)(m0 + row) * ITEMS + gc]);
                }
            }
        }
    };
    auto softbar = [&]() {
        asm volatile("s_waitcnt lgkmcnt(0)" ::: "memory");
        __builtin_amdgcn_s_barrier();
    };

    LOADA(0, a0h, a0l);
    LOADA(1, a1h, a1l);
    COMP(a0h, a0l, 0);
    softbar();
    for (int t = 1; t < 64; ++t) {
        if (t + 1 < 64) {
            if ((t + 1) & 1) LOADA(t + 1, a1h, a1l);
            else             LOADA(t + 1, a0h, a0l);
        }
        if (t & 1) COMP(a1h, a1l, 1);
        else       COMP(a0h, a0l, 0);
        FLUSH(t - 1, (t - 1) & 1);
        softbar();
    }
    FLUSH(63, 1);
}

extern "C" void kernel_launch(void* const* d_in, const int* in_sizes, int n_in,
                              void* d_out, int out_size, void* d_ws, size_t ws_size,
                              hipStream_t stream) {
    const int* category = (const int*)d_in[0];
    const int* sub_cat  = (const int*)d_in[1];
    const int* element  = (const int*)d_in[2];
    const int* brand    = (const int*)d_in[3];
    const int* pid      = (const int*)d_in[4];
    const float* price  = (const float*)d_in[5];
    const int* edge     = (const int*)d_in[6];
    const float* ecat   = (const float*)d_in[8];
    const float* esub   = (const float*)d_in[9];
    const float* eel    = (const float*)d_in[10];
    const float* ebr    = (const float*)d_in[11];
    const float* eitem  = (const float*)d_in[12];
    const float* Wm     = (const float*)d_in[13];
    const float* bm     = (const float*)d_in[14];
    const float* W_ih   = (const float*)d_in[15];
    const float* b_ih   = (const float*)d_in[16];
    const float* W_hh   = (const float*)d_in[17];
    const float* b_hh   = (const float*)d_in[18];
    const float* Wg1    = (const float*)d_in[19];
    const float* bg1    = (const float*)d_in[20];
    const float* Wg2    = (const float*)d_in[21];
    // d_in[22] = bg2 (cancels in softmax)
    const float* Wfc    = (const float*)d_in[23];
    const float* bfc    = (const float*)d_in[24];
    float* out = (float*)d_out;

    // ---- workspace carve-up (bytes), 256B-aligned regions ----
    char* p = (char*)d_ws;
    auto alloc = [&](size_t bytes) { char* r = p; p += (bytes + 255) & ~(size_t)255; return r; };
    u16* Xhi   = (u16*)alloc((size_t)NN * KP * 2);
    float* h   = (float*)alloc((size_t)NN * HH * 4);
    u16* hhi   = (u16*)alloc((size_t)NN * HH * 2);
    float* msg = (float*)alloc((size_t)NN * HH * 4);
    float* cnt = (float*)alloc((size_t)NN * 4);
    u16* phi   = (u16*)alloc((size_t)GG * HH * 2);
    u16* plo   = (u16*)alloc((size_t)GG * HH * 2);
    u16* Wmhi  = (u16*)alloc((size_t)HH * KP * 2);
    u16* Wihhi = (u16*)alloc((size_t)3 * HH * HH * 2);
    u16* Whhhi = (u16*)alloc((size_t)3 * HH * HH * 2);
    u16* Wg1hi = (u16*)alloc((size_t)HH * HH * 2);

    hipMemsetAsync(msg, 0, (size_t)NN * HH * sizeof(float), stream);
    hipMemsetAsync(cnt, 0, (size_t)NN * sizeof(float), stream);

    // weight conversions (hi-only)
    k_cvt_wm<<<(HH * KP + 255) / 256, 256, 0, stream>>>(Wm, Wmhi);
    k_cvt_hi<<<(3 * HH * HH + 255) / 256, 256, 0, stream>>>(W_ih, Wihhi, 3 * HH * HH);
    k_cvt_hi<<<(3 * HH * HH + 255) / 256, 256, 0, stream>>>(W_hh, Whhhi, 3 * HH * HH);
    k_cvt_hi<<<(HH * HH + 255) / 256, 256, 0, stream>>>(Wg1, Wg1hi, HH * HH);

    // 1. embedding gather -> X hi
    k_embed<<<NN / 4, 256, 0, stream>>>(category, sub_cat, element, brand, pid, price,
                                        ecat, esub, eel, ebr, eitem, Xhi);
    // 2. h = X @ Wm^T + bm
    k_mlp1<<<NN / 128, 256, 0, stream>>>(Xhi, Wmhi, bm, h, hhi);
    // 3. scatter (mean fused into k_gru)
    k_scatter<<<EE / 16, 256, 0, stream>>>(h, edge, msg, cnt);
    // 4. fused GRU (updates h, hhi in place)
    k_gru<<<NN / 32, 256, 0, stream>>>(msg, cnt, hhi, Wihhi, Whhhi,
                                       b_ih, b_hh, h, hhi);
    // 5. fused gate + softmax + pool -> pooled pair
    k_gatepool<<<NN / 128, 256, 0, stream>>>(hhi, h, Wg1hi, bg1, Wg2, phi, plo);
    // 6. out = pooled @ Wfc^T + bfc
    k_fc11<<<dim3(98, 4), 256, 0, stream>>>(Wfc, phi, plo, bfc, out);
}

// Round 15
// 442.705 us; speedup vs baseline: 1.2662x; 1.0138x over previous
//
#include <hip/hip_runtime.h>
#include <hip/hip_bf16.h>
#include <cstdint>
#include <cstddef>

#define NN 65536
#define EE 131072
#define GG 4096
#define HH 128
#define DD 64
#define KP 384        // padded input-feature K (321 -> 384)
#define ITEMS 50000

typedef __attribute__((ext_vector_type(8))) short bf16x8;
typedef __attribute__((ext_vector_type(4))) float f32x4;
typedef unsigned short u16;
typedef __attribute__((ext_vector_type(4))) unsigned short u16x4;

#define PINV(x) asm volatile("" : "+v"(x))

__device__ inline void split2(float x, u16* hi, u16* lo) {
    __hip_bfloat16 h = __float2bfloat16(x);
    float hf = __bfloat162float(h);
    __hip_bfloat16 l = __float2bfloat16(x - hf);
    *hi = *reinterpret_cast<u16*>(&h);
    *lo = *reinterpret_cast<u16*>(&l);
}
__device__ inline u16 hi_only(float x) {
    __hip_bfloat16 h = __float2bfloat16(x);
    return *reinterpret_cast<u16*>(&h);
}
__device__ inline float bf2f(u16 v) {
    unsigned int u = ((unsigned int)v) << 16;
    return *reinterpret_cast<float*>(&u);
}

// ---------------- embedding gather -> Xhi[N][384] (bf16 hi only) ----------------
__global__ void k_embed(const int* __restrict__ cat, const int* __restrict__ sub,
                        const int* __restrict__ el, const int* __restrict__ br,
                        const int* __restrict__ pid, const float* __restrict__ price,
                        const float* __restrict__ ecat, const float* __restrict__ esub,
                        const float* __restrict__ eel, const float* __restrict__ ebr,
                        const float* __restrict__ eitem, u16* __restrict__ Xhi) {
    int tid = threadIdx.x;
    int n = blockIdx.x * 4 + (tid >> 6);
    int l = tid & 63;
    u16* xh = Xhi + (size_t)n * KP;
    if (l == 0) xh[0] = hi_only(price[n]);
    xh[1 + l]   = hi_only(ecat[(size_t)cat[n] * DD + l]);
    xh[65 + l]  = hi_only(esub[(size_t)sub[n] * DD + l]);
    xh[129 + l] = hi_only(eel [(size_t)el[n]  * DD + l]);
    xh[193 + l] = hi_only(ebr [(size_t)br[n]  * DD + l]);
    xh[257 + l] = hi_only(eitem[(size_t)pid[n]* DD + l]);
    if (l < 63) xh[321 + l] = 0;
}

// ---------------- fp32 -> bf16 hi only ----------------
__global__ void k_cvt_hi(const float* __restrict__ src, u16* __restrict__ hi, int n_total) {
    int i = blockIdx.x * 256 + threadIdx.x;
    if (i >= n_total) return;
    hi[i] = hi_only(src[i]);
}

// ---------------- Wm (128x321) -> hi padded to (128x384) ----------------
__global__ void k_cvt_wm(const float* __restrict__ Wm, u16* __restrict__ hi) {
    int i = blockIdx.x * 256 + threadIdx.x;   // < 128*384
    int r = i / KP, c = i - r * KP;
    float x = (c < 321) ? Wm[r * 321 + c] : 0.f;
    hi[i] = hi_only(x);
}

// ---------------- h = X @ Wm^T + bm  (1-pass MFMA, emits f32 + hi) ----------------
#define M1_STR 132
__launch_bounds__(256, 2)
__global__ void k_mlp1(const u16* __restrict__ Xhi, const u16* __restrict__ Whi,
                       const float* __restrict__ bm, float* __restrict__ h,
                       u16* __restrict__ hhi) {
    __shared__ float ls[128 * M1_STR];
    int tid = threadIdx.x, w = tid >> 6, l = tid & 63;
    int lr = l & 15, lk = l >> 4;
    int m0 = blockIdx.x * 128;
    f32x4 acc[2][8];
    #pragma unroll
    for (int rt = 0; rt < 2; ++rt)
        #pragma unroll
        for (int ci = 0; ci < 8; ++ci) acc[rt][ci] = (f32x4){0.f, 0.f, 0.f, 0.f};

    for (int kc = 0; kc < 12; ++kc) {
        bf16x8 ah[2];
        #pragma unroll
        for (int rt = 0; rt < 2; ++rt) {
            size_t off = (size_t)(m0 + w * 32 + rt * 16 + lr) * KP + kc * 32 + lk * 8;
            ah[rt] = *(const bf16x8*)(Xhi + off);
        }
        #pragma unroll
        for (int ci = 0; ci < 8; ++ci) {
            size_t boff = (size_t)(ci * 16 + lr) * KP + kc * 32 + lk * 8;
            bf16x8 bh = *(const bf16x8*)(Whi + boff);
            #pragma unroll
            for (int rt = 0; rt < 2; ++rt)
                acc[rt][ci] = __builtin_amdgcn_mfma_f32_16x16x32_bf16(ah[rt], bh, acc[rt][ci], 0, 0, 0);
        }
    }
    #pragma unroll
    for (int rt = 0; rt < 2; ++rt)
        #pragma unroll
        for (int ci = 0; ci < 8; ++ci) {
            int col = ci * 16 + lr;
            float bv = bm[col];
            #pragma unroll
            for (int q = 0; q < 4; ++q)
                ls[(w * 32 + rt * 16 + lk * 4 + q) * M1_STR + col] = acc[rt][ci][q] + bv;
        }
    __syncthreads();
    int row = tid >> 1, cb = (tid & 1) * 64;
    float* hd = h + (size_t)(m0 + row) * HH + cb;
    u16* hh = hhi + (size_t)(m0 + row) * HH + cb;
    #pragma unroll
    for (int i = 0; i < 64; i += 4) {
        float4 v = *(const float4*)&ls[row * M1_STR + cb + i];
        *(float4*)(hd + i) = v;
        u16x4 vh;
        vh.x = hi_only(v.x); vh.y = hi_only(v.y);
        vh.z = hi_only(v.z); vh.w = hi_only(v.w);
        *(u16x4*)(hh + i) = vh;
    }
}

// ---------------- edge scatter: msg[dst] += bf16(h[src]); cnt[dst] += 1 ----------------
// Gathers from hhi (bf16) - halves gather bytes; values are bf16-rounded
// downstream anyway (GRU rounds the mean to bf16 for MFMA).
__global__ void k_scatter(const u16* __restrict__ hhi, const int* __restrict__ edge,
                          float* __restrict__ msg, float* __restrict__ cnt) {
    int j = threadIdx.x & 127;
    int eo = threadIdx.x >> 7;
    int e0 = blockIdx.x * 16;
    #pragma unroll
    for (int it = 0; it < 8; ++it) {
        int e = e0 + it * 2 + eo;
        int s = edge[e];
        int d = edge[EE + e];
        atomicAdd(&msg[(size_t)d * HH + j], bf2f(hhi[(size_t)s * HH + j]));
        if (j == 0) atomicAdd(&cnt[d], 1.0f);
    }
}

// ---------------- fused GRU: mean + both GEMMs (1-pass) + gates ----------------
#define GRU_STR 136
__launch_bounds__(256, 2)
__global__ void k_gru(const float* __restrict__ msg, const float* __restrict__ cnt,
                      const u16* __restrict__ hhi_in,
                      const u16* __restrict__ Wihh, const u16* __restrict__ Whhh,
                      const float* __restrict__ b_ih, const float* __restrict__ b_hh,
                      float* __restrict__ h, u16* __restrict__ hhi) {
    __shared__ float ls[32 * GRU_STR];
    int tid = threadIdx.x, w = tid >> 6, l = tid & 63;
    int lr = l & 15, lk = l >> 4;
    int m0 = blockIdx.x * 32;
    f32x4 acc[6][2][2];
    #pragma unroll
    for (int g = 0; g < 6; ++g)
        #pragma unroll
        for (int ct = 0; ct < 2; ++ct)
            #pragma unroll
            for (int rt = 0; rt < 2; ++rt) acc[g][ct][rt] = (f32x4){0.f, 0.f, 0.f, 0.f};

    float cinv[2];
    const float* mrow[2];
    #pragma unroll
    for (int rt = 0; rt < 2; ++rt) {
        int row = m0 + rt * 16 + lr;
        cinv[rt] = 1.0f / fmaxf(cnt[row], 1.0f);
        mrow[rt] = msg + (size_t)row * HH + lk * 8;
    }

    for (int kc = 0; kc < 4; ++kc) {
        bf16x8 amh[2], ahh[2];
        #pragma unroll
        for (int rt = 0; rt < 2; ++rt) {
            float4 v0 = *(const float4*)(mrow[rt] + kc * 32);
            float4 v1 = *(const float4*)(mrow[rt] + kc * 32 + 4);
            float xs[8] = {v0.x * cinv[rt], v0.y * cinv[rt], v0.z * cinv[rt], v0.w * cinv[rt],
                           v1.x * cinv[rt], v1.y * cinv[rt], v1.z * cinv[rt], v1.w * cinv[rt]};
            #pragma unroll
            for (int q = 0; q < 8; ++q) amh[rt][q] = (short)hi_only(xs[q]);
            size_t off = (size_t)(m0 + rt * 16 + lr) * HH + kc * 32 + lk * 8;
            ahh[rt] = *(const bf16x8*)(hhi_in + off);
        }
        #pragma unroll
        for (int g = 0; g < 6; ++g) {
            const u16* WH = (g < 3) ? Wihh : Whhh;
            int gb = (g % 3) * HH;
            #pragma unroll
            for (int ct = 0; ct < 2; ++ct) {
                size_t boff = (size_t)(gb + w * 32 + ct * 16 + lr) * HH + kc * 32 + lk * 8;
                bf16x8 bh = *(const bf16x8*)(WH + boff);
                #pragma unroll
                for (int rt = 0; rt < 2; ++rt) {
                    bf16x8 ah = (g < 3) ? amh[rt] : ahh[rt];
                    acc[g][ct][rt] = __builtin_amdgcn_mfma_f32_16x16x32_bf16(ah, bh, acc[g][ct][rt], 0, 0, 0);
                }
            }
        }
    }
    #pragma unroll
    for (int ct = 0; ct < 2; ++ct) {
        int col = w * 32 + ct * 16 + lr;
        float bir = b_ih[col], biz = b_ih[HH + col], bin = b_ih[2 * HH + col];
        float bhr = b_hh[col], bhz = b_hh[HH + col], bhn = b_hh[2 * HH + col];
        #pragma unroll
        for (int rt = 0; rt < 2; ++rt)
            #pragma unroll
            for (int q = 0; q < 4; ++q) {
                int rl = rt * 16 + lk * 4 + q;
                float gir = acc[0][ct][rt][q] + bir;
                float giz = acc[1][ct][rt][q] + biz;
                float gin = acc[2][ct][rt][q] + bin;
                float ghr = acc[3][ct][rt][q] + bhr;
                float ghz = acc[4][ct][rt][q] + bhz;
                float ghn = acc[5][ct][rt][q] + bhn;
                float hv = h[(size_t)(m0 + rl) * HH + col];
                float r = 1.f / (1.f + expf(-(gir + ghr)));
                float z = 1.f / (1.f + expf(-(giz + ghz)));
                float nn = tanhf(gin + r * ghn);
                ls[rl * GRU_STR + col] = (1.f - z) * nn + z * hv;
            }
    }
    __syncthreads();
    int row = tid >> 3, cb = (tid & 7) * 16;
    float* hd = h + (size_t)(m0 + row) * HH + cb;
    u16* hh = hhi + (size_t)(m0 + row) * HH + cb;
    #pragma unroll
    for (int i = 0; i < 16; i += 4) {
        float4 v = *(const float4*)&ls[row * GRU_STR + cb + i];
        *(float4*)(hd + i) = v;
        u16x4 vh;
        vh.x = hi_only(v.x); vh.y = hi_only(v.y);
        vh.z = hi_only(v.z); vh.w = hi_only(v.w);
        *(u16x4*)(hh + i) = vh;
    }
}

// ---------------- fused gate + segment-softmax + pool + split ----------------
__launch_bounds__(256, 2)
__global__ void k_gatepool(const u16* __restrict__ hhi, const float* __restrict__ h,
                           const u16* __restrict__ Ghi, const float* __restrict__ bg1,
                           const float* __restrict__ Wg2,
                           u16* __restrict__ phi, u16* __restrict__ plo) {
    __shared__ float sal[128];
    int tid = threadIdx.x, w = tid >> 6, l = tid & 63;
    int lr = l & 15, lk = l >> 4;
    int m0 = blockIdx.x * 128;
    f32x4 acc[2][8];
    #pragma unroll
    for (int rt = 0; rt < 2; ++rt)
        #pragma unroll
        for (int ci = 0; ci < 8; ++ci) acc[rt][ci] = (f32x4){0.f, 0.f, 0.f, 0.f};

    for (int kc = 0; kc < 4; ++kc) {
        bf16x8 ah[2];
        #pragma unroll
        for (int rt = 0; rt < 2; ++rt) {
            size_t off = (size_t)(m0 + w * 32 + rt * 16 + lr) * HH + kc * 32 + lk * 8;
            ah[rt] = *(const bf16x8*)(hhi + off);
        }
        #pragma unroll
        for (int ci = 0; ci < 8; ++ci) {
            size_t boff = (size_t)(ci * 16 + lr) * HH + kc * 32 + lk * 8;
            bf16x8 bh = *(const bf16x8*)(Ghi + boff);
            #pragma unroll
            for (int rt = 0; rt < 2; ++rt)
                acc[rt][ci] = __builtin_amdgcn_mfma_f32_16x16x32_bf16(ah[rt], bh, acc[rt][ci], 0, 0, 0);
        }
    }
    float part[2][4] = {};
    #pragma unroll
    for (int ci = 0; ci < 8; ++ci) {
        int col = ci * 16 + lr;
        float wv = Wg2[col], bb = bg1[col];
        #pragma unroll
        for (int rt = 0; rt < 2; ++rt)
            #pragma unroll
            for (int q = 0; q < 4; ++q)
                part[rt][q] += fmaxf(acc[rt][ci][q] + bb, 0.f) * wv;
    }
    #pragma unroll
    for (int rt = 0; rt < 2; ++rt)
        #pragma unroll
        for (int q = 0; q < 4; ++q) {
            float v = part[rt][q];
            v += __shfl_xor(v, 1);
            v += __shfl_xor(v, 2);
            v += __shfl_xor(v, 4);
            v += __shfl_xor(v, 8);
            part[rt][q] = v;
        }
    if (lr == 0) {
        #pragma unroll
        for (int rt = 0; rt < 2; ++rt)
            #pragma unroll
            for (int q = 0; q < 4; ++q)
                sal[w * 32 + rt * 16 + lk * 4 + q] = part[rt][q];
    }
    __syncthreads();

    int g2 = tid >> 5;
    int c = (tid & 31) * 4;
    int rb = g2 * 16;
    float gv[16];
    float mx = -1e30f;
    #pragma unroll
    for (int i = 0; i < 16; ++i) { gv[i] = sal[rb + i]; mx = fmaxf(mx, gv[i]); }
    float den = 0.f;
    #pragma unroll
    for (int i = 0; i < 16; ++i) { gv[i] = expf(gv[i] - mx); den += gv[i]; }
    float inv = 1.f / den;
    f32x4 a = (f32x4){0.f, 0.f, 0.f, 0.f};
    #pragma unroll
    for (int i = 0; i < 16; ++i) {
        float4 hv = *(const float4*)&h[(size_t)(m0 + rb + i) * HH + c];
        float wgt = gv[i] * inv;
        a[0] += wgt * hv.x; a[1] += wgt * hv.y; a[2] += wgt * hv.z; a[3] += wgt * hv.w;
    }
    size_t po = (size_t)(blockIdx.x * 8 + g2) * HH + c;
    u16x4 vh, vl;
    #pragma unroll
    for (int q = 0; q < 4; ++q) split2(a[q], (u16*)&vh + q, (u16*)&vl + q);
    *(u16x4*)(phi + po) = vh;
    *(u16x4*)(plo + po) = vl;
}

// ---------------- FC v12: fc11 + XCD-coherent strip mapping ----------------
// 1D grid 416. Decode: xcd = wg%8, r = wg/8, strip = (r/4)*8 + xcd, phase = r%4.
// All 4 row-phases of a column strip share linear%8 -> same XCD (heuristic) ->
// the strip's 256KB of Wfc stays in that XCD's L2 across phases.
// Structure otherwise = fc11: 256 thr / 2 blocks per CU, 512-col strip, W-hi
// pinned regs, 2-deep A prefetch, lgkm-only barrier, nt stores, 2KB/row FLUSH.
#define FC_STR 520
__launch_bounds__(256, 2)
__global__ void k_fc12(const float* __restrict__ Wfc,
                       const u16* __restrict__ phi, const u16* __restrict__ plo,
                       const float* __restrict__ bfc, float* __restrict__ out) {
    __shared__ float ls[2][16][FC_STR];
    int wg = blockIdx.x;
    int xcd = wg & 7;
    int r = wg >> 3;
    int strip = (r >> 2) * 8 + xcd;
    int phase = r & 3;
    if (strip >= 98) return;
    int tid = threadIdx.x, w = tid >> 6, l = tid & 63;
    int lr = l & 15, lk = l >> 4;
    int c0 = strip * 512;
    int mbase = phase * 1024;

    bf16x8 bh[8][4];
    float bias[8];
    #pragma unroll
    for (int ci = 0; ci < 8; ++ci) {
        int n = c0 + w * 128 + ci * 16 + lr;
        bool ok = (n < ITEMS);
        const float* Wr = Wfc + (size_t)n * HH;
        #pragma unroll
        for (int kc = 0; kc < 4; ++kc) {
            float4 v0 = ok ? *(const float4*)(Wr + kc * 32 + lk * 8)     : make_float4(0.f,0.f,0.f,0.f);
            float4 v1 = ok ? *(const float4*)(Wr + kc * 32 + lk * 8 + 4) : make_float4(0.f,0.f,0.f,0.f);
            float xs[8] = {v0.x, v0.y, v0.z, v0.w, v1.x, v1.y, v1.z, v1.w};
            bf16x8 hv;
            #pragma unroll
            for (int q = 0; q < 8; ++q) hv[q] = (short)hi_only(xs[q]);
            bh[ci][kc] = hv;
        }
        bias[ci] = ok ? bfc[n] : 0.f;
    }
    #pragma unroll
    for (int ci = 0; ci < 8; ++ci)
        #pragma unroll
        for (int kc = 0; kc < 4; ++kc) PINV(bh[ci][kc]);

    bf16x8 a0h[4], a0l[4], a1h[4], a1l[4];
    auto LOADA = [&](int t, bf16x8* Ah, bf16x8* Al) {
        int m0 = mbase + t * 16;
        size_t aoff = (size_t)(m0 + lr) * HH + lk * 8;
        #pragma unroll
        for (int kc = 0; kc < 4; ++kc) {
            Ah[kc] = *(const bf16x8*)(phi + aoff + kc * 32);
            Al[kc] = *(const bf16x8*)(plo + aoff + kc * 32);
        }
    };
    auto COMP = [&](const bf16x8* Ah, const bf16x8* Al, int b) {
        #pragma unroll
        for (int ci = 0; ci < 8; ++ci) {
            f32x4 acc = (f32x4){0.f, 0.f, 0.f, 0.f};
            #pragma unroll
            for (int kc = 0; kc < 4; ++kc) {
                acc = __builtin_amdgcn_mfma_f32_16x16x32_bf16(Ah[kc], bh[ci][kc], acc, 0, 0, 0);
                acc = __builtin_amdgcn_mfma_f32_16x16x32_bf16(Al[kc], bh[ci][kc], acc, 0, 0, 0);
            }
            #pragma unroll
            for (int q = 0; q < 4; ++q)
                ls[b][lk * 4 + q][w * 128 + ci * 16 + lr] = acc[q] + bias[ci];
        }
    };
    auto FLUSH = [&](int t, int b) {
        int m0 = mbase + t * 16;
        #pragma unroll
        for (int p = 0; p < 4; ++p) {
            int row = w * 4 + p;
            #pragma unroll
            for (int s = 0; s < 2; ++s) {
                int c = s * 256 + l * 4;
                int gc = c0 + c;
                if (gc < ITEMS) {
                    f32x4 v = *(const f32x4*)&ls[b][row][c];
                    __builtin_nontemporal_store(v, (f32x4*)&out[(size_t)(m0 + row) * ITEMS + gc]);
                }
            }
        }
    };
    auto softbar = [&]() {
        asm volatile("s_waitcnt lgkmcnt(0)" ::: "memory");
        __builtin_amdgcn_s_barrier();
    };

    LOADA(0, a0h, a0l);
    LOADA(1, a1h, a1l);
    COMP(a0h, a0l, 0);
    softbar();
    for (int t = 1; t < 64; ++t) {
        if (t + 1 < 64) {
            if ((t + 1) & 1) LOADA(t + 1, a1h, a1l);
            else             LOADA(t + 1, a0h, a0l);
        }
        if (t & 1) COMP(a1h, a1l, 1);
        else       COMP(a0h, a0l, 0);
        FLUSH(t - 1, (t - 1) & 1);
        softbar();
    }
    FLUSH(63, 1);
}

extern "C" void kernel_launch(void* const* d_in, const int* in_sizes, int n_in,
                              void* d_out, int out_size, void* d_ws, size_t ws_size,
                              hipStream_t stream) {
    const int* category = (const int*)d_in[0];
    const int* sub_cat  = (const int*)d_in[1];
    const int* element  = (const int*)d_in[2];
    const int* brand    = (const int*)d_in[3];
    const int* pid      = (const int*)d_in[4];
    const float* price  = (const float*)d_in[5];
    const int* edge     = (const int*)d_in[6];
    const float* ecat   = (const float*)d_in[8];
    const float* esub   = (const float*)d_in[9];
    const float* eel    = (const float*)d_in[10];
    const float* ebr    = (const float*)d_in[11];
    const float* eitem  = (const float*)d_in[12];
    const float* Wm     = (const float*)d_in[13];
    const float* bm     = (const float*)d_in[14];
    const float* W_ih   = (const float*)d_in[15];
    const float* b_ih   = (const float*)d_in[16];
    const float* W_hh   = (const float*)d_in[17];
    const float* b_hh   = (const float*)d_in[18];
    const float* Wg1    = (const float*)d_in[19];
    const float* bg1    = (const float*)d_in[20];
    const float* Wg2    = (const float*)d_in[21];
    // d_in[22] = bg2 (cancels in softmax)
    const float* Wfc    = (const float*)d_in[23];
    const float* bfc    = (const float*)d_in[24];
    float* out = (float*)d_out;

    // ---- workspace carve-up (bytes), 256B-aligned regions ----
    char* p = (char*)d_ws;
    auto alloc = [&](size_t bytes) { char* r = p; p += (bytes + 255) & ~(size_t)255; return r; };
    u16* Xhi   = (u16*)alloc((size_t)NN * KP * 2);
    float* h   = (float*)alloc((size_t)NN * HH * 4);
    u16* hhi   = (u16*)alloc((size_t)NN * HH * 2);
    float* msg = (float*)alloc((size_t)NN * HH * 4);
    float* cnt = (float*)alloc((size_t)NN * 4);
    u16* phi   = (u16*)alloc((size_t)GG * HH * 2);
    u16* plo   = (u16*)alloc((size_t)GG * HH * 2);
    u16* Wmhi  = (u16*)alloc((size_t)HH * KP * 2);
    u16* Wihhi = (u16*)alloc((size_t)3 * HH * HH * 2);
    u16* Whhhi = (u16*)alloc((size_t)3 * HH * HH * 2);
    u16* Wg1hi = (u16*)alloc((size_t)HH * HH * 2);

    hipMemsetAsync(msg, 0, (size_t)NN * HH * sizeof(float), stream);
    hipMemsetAsync(cnt, 0, (size_t)NN * sizeof(float), stream);

    // weight conversions (hi-only)
    k_cvt_wm<<<(HH * KP + 255) / 256, 256, 0, stream>>>(Wm, Wmhi);
    k_cvt_hi<<<(3 * HH * HH + 255) / 256, 256, 0, stream>>>(W_ih, Wihhi, 3 * HH * HH);
    k_cvt_hi<<<(3 * HH * HH + 255) / 256, 256, 0, stream>>>(W_hh, Whhhi, 3 * HH * HH);
    k_cvt_hi<<<(HH * HH + 255) / 256, 256, 0, stream>>>(Wg1, Wg1hi, HH * HH);

    // 1. embedding gather -> X hi
    k_embed<<<NN / 4, 256, 0, stream>>>(category, sub_cat, element, brand, pid, price,
                                        ecat, esub, eel, ebr, eitem, Xhi);
    // 2. h = X @ Wm^T + bm
    k_mlp1<<<NN / 128, 256, 0, stream>>>(Xhi, Wmhi, bm, h, hhi);
    // 3. scatter (bf16 gather; mean fused into k_gru)
    k_scatter<<<EE / 16, 256, 0, stream>>>(hhi, edge, msg, cnt);
    // 4. fused GRU (updates h, hhi in place)
    k_gru<<<NN / 32, 256, 0, stream>>>(msg, cnt, hhi, Wihhi, Whhhi,
                                       b_ih, b_hh, h, hhi);
    // 5. fused gate + softmax + pool -> pooled pair
    k_gatepool<<<NN / 128, 256, 0, stream>>>(hhi, h, Wg1hi, bg1, Wg2, phi, plo);
    // 6. out = pooled @ Wfc^T + bfc (XCD-coherent strips)
    k_fc12<<<dim3(416), 256, 0, stream>>>(Wfc, phi, plo, bfc, out);
}

// Round 16
// 423.469 us; speedup vs baseline: 1.3237x; 1.0454x over previous
//
#include <hip/hip_runtime.h>
#include <hip/hip_bf16.h>
#include <cstdint>
#include <cstddef>

#define NN 65536
#define EE 131072
#define GG 4096
#define HH 128
#define DD 64
#define KP 384        // padded input-feature K (321 -> 384)
#define ITEMS 50000
#define NPAD 50176    // 98 * 512

typedef __attribute__((ext_vector_type(8))) short bf16x8;
typedef __attribute__((ext_vector_type(4))) float f32x4;
typedef unsigned short u16;
typedef __attribute__((ext_vector_type(4))) unsigned short u16x4;

#define PINV(x) asm volatile("" : "+v"(x))

__device__ inline void split2(float x, u16* hi, u16* lo) {
    __hip_bfloat16 h = __float2bfloat16(x);
    float hf = __bfloat162float(h);
    __hip_bfloat16 l = __float2bfloat16(x - hf);
    *hi = *reinterpret_cast<u16*>(&h);
    *lo = *reinterpret_cast<u16*>(&l);
}
__device__ inline u16 hi_only(float x) {
    __hip_bfloat16 h = __float2bfloat16(x);
    return *reinterpret_cast<u16*>(&h);
}
__device__ inline float bf2f(u16 v) {
    unsigned int u = ((unsigned int)v) << 16;
    return *reinterpret_cast<float*>(&u);
}

// ---------------- embedding gather -> Xhi[N][384] (bf16 hi only) ----------------
__global__ void k_embed(const int* __restrict__ cat, const int* __restrict__ sub,
                        const int* __restrict__ el, const int* __restrict__ br,
                        const int* __restrict__ pid, const float* __restrict__ price,
                        const float* __restrict__ ecat, const float* __restrict__ esub,
                        const float* __restrict__ eel, const float* __restrict__ ebr,
                        const float* __restrict__ eitem, u16* __restrict__ Xhi) {
    int tid = threadIdx.x;
    int n = blockIdx.x * 4 + (tid >> 6);
    int l = tid & 63;
    u16* xh = Xhi + (size_t)n * KP;
    if (l == 0) xh[0] = hi_only(price[n]);
    xh[1 + l]   = hi_only(ecat[(size_t)cat[n] * DD + l]);
    xh[65 + l]  = hi_only(esub[(size_t)sub[n] * DD + l]);
    xh[129 + l] = hi_only(eel [(size_t)el[n]  * DD + l]);
    xh[193 + l] = hi_only(ebr [(size_t)br[n]  * DD + l]);
    xh[257 + l] = hi_only(eitem[(size_t)pid[n]* DD + l]);
    if (l < 63) xh[321 + l] = 0;
}

// ---------------- fp32 -> bf16 hi only (with zero-pad past n_valid) ----------------
__global__ void k_cvt_hi(const float* __restrict__ src, u16* __restrict__ hi,
                         int n_valid, int n_total) {
    int i = blockIdx.x * 256 + threadIdx.x;
    if (i >= n_total) return;
    hi[i] = (i < n_valid) ? hi_only(src[i]) : (u16)0;
}

// ---------------- Wm (128x321) -> hi padded to (128x384) ----------------
__global__ void k_cvt_wm(const float* __restrict__ Wm, u16* __restrict__ hi) {
    int i = blockIdx.x * 256 + threadIdx.x;   // < 128*384
    int r = i / KP, c = i - r * KP;
    float x = (c < 321) ? Wm[r * 321 + c] : 0.f;
    hi[i] = hi_only(x);
}

// ---------------- h = X @ Wm^T + bm  (1-pass MFMA, emits hi/lo pair) ----------------
#define M1_STR 132
__launch_bounds__(256, 2)
__global__ void k_mlp1(const u16* __restrict__ Xhi, const u16* __restrict__ Whi,
                       const float* __restrict__ bm,
                       u16* __restrict__ hhi, u16* __restrict__ hlo) {
    __shared__ float ls[128 * M1_STR];
    int tid = threadIdx.x, w = tid >> 6, l = tid & 63;
    int lr = l & 15, lk = l >> 4;
    int m0 = blockIdx.x * 128;
    f32x4 acc[2][8];
    #pragma unroll
    for (int rt = 0; rt < 2; ++rt)
        #pragma unroll
        for (int ci = 0; ci < 8; ++ci) acc[rt][ci] = (f32x4){0.f, 0.f, 0.f, 0.f};

    for (int kc = 0; kc < 12; ++kc) {
        bf16x8 ah[2];
        #pragma unroll
        for (int rt = 0; rt < 2; ++rt) {
            size_t off = (size_t)(m0 + w * 32 + rt * 16 + lr) * KP + kc * 32 + lk * 8;
            ah[rt] = *(const bf16x8*)(Xhi + off);
        }
        #pragma unroll
        for (int ci = 0; ci < 8; ++ci) {
            size_t boff = (size_t)(ci * 16 + lr) * KP + kc * 32 + lk * 8;
            bf16x8 bh = *(const bf16x8*)(Whi + boff);
            #pragma unroll
            for (int rt = 0; rt < 2; ++rt)
                acc[rt][ci] = __builtin_amdgcn_mfma_f32_16x16x32_bf16(ah[rt], bh, acc[rt][ci], 0, 0, 0);
        }
    }
    #pragma unroll
    for (int rt = 0; rt < 2; ++rt)
        #pragma unroll
        for (int ci = 0; ci < 8; ++ci) {
            int col = ci * 16 + lr;
            float bv = bm[col];
            #pragma unroll
            for (int q = 0; q < 4; ++q)
                ls[(w * 32 + rt * 16 + lk * 4 + q) * M1_STR + col] = acc[rt][ci][q] + bv;
        }
    __syncthreads();
    int row = tid >> 1, cb = (tid & 1) * 64;
    u16* hh = hhi + (size_t)(m0 + row) * HH + cb;
    u16* hl = hlo + (size_t)(m0 + row) * HH + cb;
    #pragma unroll
    for (int i = 0; i < 64; i += 4) {
        float4 v = *(const float4*)&ls[row * M1_STR + cb + i];
        u16x4 vh, vl;
        split2(v.x, (u16*)&vh + 0, (u16*)&vl + 0);
        split2(v.y, (u16*)&vh + 1, (u16*)&vl + 1);
        split2(v.z, (u16*)&vh + 2, (u16*)&vl + 2);
        split2(v.w, (u16*)&vh + 3, (u16*)&vl + 3);
        *(u16x4*)(hh + i) = vh;
        *(u16x4*)(hl + i) = vl;
    }
}

// ---------------- edge scatter: msg[dst] += bf16(h[src]); cnt[dst] += 1 ----------------
__global__ void k_scatter(const u16* __restrict__ hhi, const int* __restrict__ edge,
                          float* __restrict__ msg, float* __restrict__ cnt) {
    int j = threadIdx.x & 127;
    int eo = threadIdx.x >> 7;
    int e0 = blockIdx.x * 16;
    #pragma unroll
    for (int it = 0; it < 8; ++it) {
        int e = e0 + it * 2 + eo;
        int s = edge[e];
        int d = edge[EE + e];
        atomicAdd(&msg[(size_t)d * HH + j], bf2f(hhi[(size_t)s * HH + j]));
        if (j == 0) atomicAdd(&cnt[d], 1.0f);
    }
}

// ---------------- fused GRU: mean + both GEMMs (1-pass) + gates; h as pair ----------------
#define GRU_STR 136
__launch_bounds__(256, 2)
__global__ void k_gru(const float* __restrict__ msg, const float* __restrict__ cnt,
                      const u16* __restrict__ Wihh, const u16* __restrict__ Whhh,
                      const float* __restrict__ b_ih, const float* __restrict__ b_hh,
                      u16* __restrict__ hhi, u16* __restrict__ hlo) {
    __shared__ float ls[32 * GRU_STR];
    int tid = threadIdx.x, w = tid >> 6, l = tid & 63;
    int lr = l & 15, lk = l >> 4;
    int m0 = blockIdx.x * 32;
    f32x4 acc[6][2][2];
    #pragma unroll
    for (int g = 0; g < 6; ++g)
        #pragma unroll
        for (int ct = 0; ct < 2; ++ct)
            #pragma unroll
            for (int rt = 0; rt < 2; ++rt) acc[g][ct][rt] = (f32x4){0.f, 0.f, 0.f, 0.f};

    float cinv[2];
    const float* mrow[2];
    #pragma unroll
    for (int rt = 0; rt < 2; ++rt) {
        int row = m0 + rt * 16 + lr;
        cinv[rt] = 1.0f / fmaxf(cnt[row], 1.0f);
        mrow[rt] = msg + (size_t)row * HH + lk * 8;
    }

    for (int kc = 0; kc < 4; ++kc) {
        bf16x8 amh[2], ahh[2];
        #pragma unroll
        for (int rt = 0; rt < 2; ++rt) {
            float4 v0 = *(const float4*)(mrow[rt] + kc * 32);
            float4 v1 = *(const float4*)(mrow[rt] + kc * 32 + 4);
            float xs[8] = {v0.x * cinv[rt], v0.y * cinv[rt], v0.z * cinv[rt], v0.w * cinv[rt],
                           v1.x * cinv[rt], v1.y * cinv[rt], v1.z * cinv[rt], v1.w * cinv[rt]};
            #pragma unroll
            for (int q = 0; q < 8; ++q) amh[rt][q] = (short)hi_only(xs[q]);
            size_t off = (size_t)(m0 + rt * 16 + lr) * HH + kc * 32 + lk * 8;
            ahh[rt] = *(const bf16x8*)(hhi + off);
        }
        #pragma unroll
        for (int g = 0; g < 6; ++g) {
            const u16* WH = (g < 3) ? Wihh : Whhh;
            int gb = (g % 3) * HH;
            #pragma unroll
            for (int ct = 0; ct < 2; ++ct) {
                size_t boff = (size_t)(gb + w * 32 + ct * 16 + lr) * HH + kc * 32 + lk * 8;
                bf16x8 bh = *(const bf16x8*)(WH + boff);
                #pragma unroll
                for (int rt = 0; rt < 2; ++rt) {
                    bf16x8 ah = (g < 3) ? amh[rt] : ahh[rt];
                    acc[g][ct][rt] = __builtin_amdgcn_mfma_f32_16x16x32_bf16(ah, bh, acc[g][ct][rt], 0, 0, 0);
                }
            }
        }
    }
    #pragma unroll
    for (int ct = 0; ct < 2; ++ct) {
        int col = w * 32 + ct * 16 + lr;
        float bir = b_ih[col], biz = b_ih[HH + col], bin = b_ih[2 * HH + col];
        float bhr = b_hh[col], bhz = b_hh[HH + col], bhn = b_hh[2 * HH + col];
        #pragma unroll
        for (int rt = 0; rt < 2; ++rt)
            #pragma unroll
            for (int q = 0; q < 4; ++q) {
                int rl = rt * 16 + lk * 4 + q;
                size_t idx = (size_t)(m0 + rl) * HH + col;
                float gir = acc[0][ct][rt][q] + bir;
                float giz = acc[1][ct][rt][q] + biz;
                float gin = acc[2][ct][rt][q] + bin;
                float ghr = acc[3][ct][rt][q] + bhr;
                float ghz = acc[4][ct][rt][q] + bhz;
                float ghn = acc[5][ct][rt][q] + bhn;
                float hv = bf2f(hhi[idx]) + bf2f(hlo[idx]);
                float r = 1.f / (1.f + expf(-(gir + ghr)));
                float z = 1.f / (1.f + expf(-(giz + ghz)));
                float nn = tanhf(gin + r * ghn);
                ls[rl * GRU_STR + col] = (1.f - z) * nn + z * hv;
            }
    }
    __syncthreads();
    int row = tid >> 3, cb = (tid & 7) * 16;
    u16* hh = hhi + (size_t)(m0 + row) * HH + cb;
    u16* hl = hlo + (size_t)(m0 + row) * HH + cb;
    #pragma unroll
    for (int i = 0; i < 16; i += 4) {
        float4 v = *(const float4*)&ls[row * GRU_STR + cb + i];
        u16x4 vh, vl;
        split2(v.x, (u16*)&vh + 0, (u16*)&vl + 0);
        split2(v.y, (u16*)&vh + 1, (u16*)&vl + 1);
        split2(v.z, (u16*)&vh + 2, (u16*)&vl + 2);
        split2(v.w, (u16*)&vh + 3, (u16*)&vl + 3);
        *(u16x4*)(hh + i) = vh;
        *(u16x4*)(hl + i) = vl;
    }
}

// ---------------- fused gate + segment-softmax + pool + split ----------------
__launch_bounds__(256, 2)
__global__ void k_gatepool(const u16* __restrict__ hhi, const u16* __restrict__ hlo,
                           const u16* __restrict__ Ghi, const float* __restrict__ bg1,
                           const float* __restrict__ Wg2,
                           u16* __restrict__ phi, u16* __restrict__ plo) {
    __shared__ float sal[128];
    int tid = threadIdx.x, w = tid >> 6, l = tid & 63;
    int lr = l & 15, lk = l >> 4;
    int m0 = blockIdx.x * 128;
    f32x4 acc[2][8];
    #pragma unroll
    for (int rt = 0; rt < 2; ++rt)
        #pragma unroll
        for (int ci = 0; ci < 8; ++ci) acc[rt][ci] = (f32x4){0.f, 0.f, 0.f, 0.f};

    for (int kc = 0; kc < 4; ++kc) {
        bf16x8 ah[2];
        #pragma unroll
        for (int rt = 0; rt < 2; ++rt) {
            size_t off = (size_t)(m0 + w * 32 + rt * 16 + lr) * HH + kc * 32 + lk * 8;
            ah[rt] = *(const bf16x8*)(hhi + off);
        }
        #pragma unroll
        for (int ci = 0; ci < 8; ++ci) {
            size_t boff = (size_t)(ci * 16 + lr) * HH + kc * 32 + lk * 8;
            bf16x8 bh = *(const bf16x8*)(Ghi + boff);
            #pragma unroll
            for (int rt = 0; rt < 2; ++rt)
                acc[rt][ci] = __builtin_amdgcn_mfma_f32_16x16x32_bf16(ah[rt], bh, acc[rt][ci], 0, 0, 0);
        }
    }
    float part[2][4] = {};
    #pragma unroll
    for (int ci = 0; ci < 8; ++ci) {
        int col = ci * 16 + lr;
        float wv = Wg2[col], bb = bg1[col];
        #pragma unroll
        for (int rt = 0; rt < 2; ++rt)
            #pragma unroll
            for (int q = 0; q < 4; ++q)
                part[rt][q] += fmaxf(acc[rt][ci][q] + bb, 0.f) * wv;
    }
    #pragma unroll
    for (int rt = 0; rt < 2; ++rt)
        #pragma unroll
        for (int q = 0; q < 4; ++q) {
            float v = part[rt][q];
            v += __shfl_xor(v, 1);
            v += __shfl_xor(v, 2);
            v += __shfl_xor(v, 4);
            v += __shfl_xor(v, 8);
            part[rt][q] = v;
        }
    if (lr == 0) {
        #pragma unroll
        for (int rt = 0; rt < 2; ++rt)
            #pragma unroll
            for (int q = 0; q < 4; ++q)
                sal[w * 32 + rt * 16 + lk * 4 + q] = part[rt][q];
    }
    __syncthreads();

    int g2 = tid >> 5;
    int c = (tid & 31) * 4;
    int rb = g2 * 16;
    float gv[16];
    float mx = -1e30f;
    #pragma unroll
    for (int i = 0; i < 16; ++i) { gv[i] = sal[rb + i]; mx = fmaxf(mx, gv[i]); }
    float den = 0.f;
    #pragma unroll
    for (int i = 0; i < 16; ++i) { gv[i] = expf(gv[i] - mx); den += gv[i]; }
    float inv = 1.f / den;
    f32x4 a = (f32x4){0.f, 0.f, 0.f, 0.f};
    #pragma unroll
    for (int i = 0; i < 16; ++i) {
        size_t idx = (size_t)(m0 + rb + i) * HH + c;
        u16x4 xh = *(const u16x4*)(hhi + idx);
        u16x4 xl = *(const u16x4*)(hlo + idx);
        float wgt = gv[i] * inv;
        a[0] += wgt * (bf2f(xh.x) + bf2f(xl.x));
        a[1] += wgt * (bf2f(xh.y) + bf2f(xl.y));
        a[2] += wgt * (bf2f(xh.z) + bf2f(xl.z));
        a[3] += wgt * (bf2f(xh.w) + bf2f(xl.w));
    }
    size_t po = (size_t)(blockIdx.x * 8 + g2) * HH + c;
    u16x4 vh, vl;
    #pragma unroll
    for (int q = 0; q < 4; ++q) split2(a[q], (u16*)&vh + q, (u16*)&vl + q);
    *(u16x4*)(phi + po) = vh;
    *(u16x4*)(plo + po) = vl;
}

// ---------------- FC v13: fc12 + pre-converted bf16 Wfc ----------------
// 1D grid 416. xcd = wg%8, r = wg/8, strip = (r/4)*8 + xcd, phase = r%4 ->
// all 4 phases of a strip on one XCD (L2-resident weights). 256 thr /
// 2 blocks per CU; 512-col strip; W-hi bf16 loads (1 x 16B per fragment),
// pinned; A = pooled hi+lo 2-pass; 2-deep prefetch; lgkm-only barrier;
// nt stores; 2KB/row FLUSH.
#define FC_STR 520
__launch_bounds__(256, 2)
__global__ void k_fc13(const u16* __restrict__ Wfcb,
                       const u16* __restrict__ phi, const u16* __restrict__ plo,
                       const float* __restrict__ bfc, float* __restrict__ out) {
    __shared__ float ls[2][16][FC_STR];
    int wg = blockIdx.x;
    int xcd = wg & 7;
    int r = wg >> 3;
    int strip = (r >> 2) * 8 + xcd;
    int phase = r & 3;
    if (strip >= 98) return;
    int tid = threadIdx.x, w = tid >> 6, l = tid & 63;
    int lr = l & 15, lk = l >> 4;
    int c0 = strip * 512;
    int mbase = phase * 1024;

    bf16x8 bh[8][4];
    float bias[8];
    #pragma unroll
    for (int ci = 0; ci < 8; ++ci) {
        int n = c0 + w * 128 + ci * 16 + lr;
        const u16* Wr = Wfcb + (size_t)n * HH + lk * 8;
        #pragma unroll
        for (int kc = 0; kc < 4; ++kc)
            bh[ci][kc] = *(const bf16x8*)(Wr + kc * 32);
        bias[ci] = (n < ITEMS) ? bfc[n] : 0.f;
    }
    #pragma unroll
    for (int ci = 0; ci < 8; ++ci)
        #pragma unroll
        for (int kc = 0; kc < 4; ++kc) PINV(bh[ci][kc]);

    bf16x8 a0h[4], a0l[4], a1h[4], a1l[4];
    auto LOADA = [&](int t, bf16x8* Ah, bf16x8* Al) {
        int m0 = mbase + t * 16;
        size_t aoff = (size_t)(m0 + lr) * HH + lk * 8;
        #pragma unroll
        for (int kc = 0; kc < 4; ++kc) {
            Ah[kc] = *(const bf16x8*)(phi + aoff + kc * 32);
            Al[kc] = *(const bf16x8*)(plo + aoff + kc * 32);
        }
    };
    auto COMP = [&](const bf16x8* Ah, const bf16x8* Al, int b) {
        #pragma unroll
        for (int ci = 0; ci < 8; ++ci) {
            f32x4 acc = (f32x4){0.f, 0.f, 0.f, 0.f};
            #pragma unroll
            for (int kc = 0; kc < 4; ++kc) {
                acc = __builtin_amdgcn_mfma_f32_16x16x32_bf16(Ah[kc], bh[ci][kc], acc, 0, 0, 0);
                acc = __builtin_amdgcn_mfma_f32_16x16x32_bf16(Al[kc], bh[ci][kc], acc, 0, 0, 0);
            }
            #pragma unroll
            for (int q = 0; q < 4; ++q)
                ls[b][lk * 4 + q][w * 128 + ci * 16 + lr] = acc[q] + bias[ci];
        }
    };
    auto FLUSH = [&](int t, int b) {
        int m0 = mbase + t * 16;
        #pragma unroll
        for (int p = 0; p < 4; ++p) {
            int row = w * 4 + p;
            #pragma unroll
            for (int s = 0; s < 2; ++s) {
                int c = s * 256 + l * 4;
                int gc = c0 + c;
                if (gc < ITEMS) {
                    f32x4 v = *(const f32x4*)&ls[b][row][c];
                    __builtin_nontemporal_store(v, (f32x4*)&out[(size_t)(m0 + row) * ITEMS + gc]);
                }
            }
        }
    };
    auto softbar = [&]() {
        asm volatile("s_waitcnt lgkmcnt(0)" ::: "memory");
        __builtin_amdgcn_s_barrier();
    };

    LOADA(0, a0h, a0l);
    LOADA(1, a1h, a1l);
    COMP(a0h, a0l, 0);
    softbar();
    for (int t = 1; t < 64; ++t) {
        if (t + 1 < 64) {
            if ((t + 1) & 1) LOADA(t + 1, a1h, a1l);
            else             LOADA(t + 1, a0h, a0l);
        }
        if (t & 1) COMP(a1h, a1l, 1);
        else       COMP(a0h, a0l, 0);
        FLUSH(t - 1, (t - 1) & 1);
        softbar();
    }
    FLUSH(63, 1);
}

extern "C" void kernel_launch(void* const* d_in, const int* in_sizes, int n_in,
                              void* d_out, int out_size, void* d_ws, size_t ws_size,
                              hipStream_t stream) {
    const int* category = (const int*)d_in[0];
    const int* sub_cat  = (const int*)d_in[1];
    const int* element  = (const int*)d_in[2];
    const int* brand    = (const int*)d_in[3];
    const int* pid      = (const int*)d_in[4];
    const float* price  = (const float*)d_in[5];
    const int* edge     = (const int*)d_in[6];
    const float* ecat   = (const float*)d_in[8];
    const float* esub   = (const float*)d_in[9];
    const float* eel    = (const float*)d_in[10];
    const float* ebr    = (const float*)d_in[11];
    const float* eitem  = (const float*)d_in[12];
    const float* Wm     = (const float*)d_in[13];
    const float* bm     = (const float*)d_in[14];
    const float* W_ih   = (const float*)d_in[15];
    const float* b_ih   = (const float*)d_in[16];
    const float* W_hh   = (const float*)d_in[17];
    const float* b_hh   = (const float*)d_in[18];
    const float* Wg1    = (const float*)d_in[19];
    const float* bg1    = (const float*)d_in[20];
    const float* Wg2    = (const float*)d_in[21];
    // d_in[22] = bg2 (cancels in softmax)
    const float* Wfc    = (const float*)d_in[23];
    const float* bfc    = (const float*)d_in[24];
    float* out = (float*)d_out;

    // ---- workspace carve-up (bytes), 256B-aligned regions ----
    char* p = (char*)d_ws;
    auto alloc = [&](size_t bytes) { char* r = p; p += (bytes + 255) & ~(size_t)255; return r; };
    u16* Xhi   = (u16*)alloc((size_t)NN * KP * 2);
    u16* hhi   = (u16*)alloc((size_t)NN * HH * 2);
    u16* hlo   = (u16*)alloc((size_t)NN * HH * 2);
    float* msg = (float*)alloc((size_t)NN * HH * 4);
    float* cnt = (float*)alloc((size_t)NN * 4);
    u16* phi   = (u16*)alloc((size_t)GG * HH * 2);
    u16* plo   = (u16*)alloc((size_t)GG * HH * 2);
    u16* Wmhi  = (u16*)alloc((size_t)HH * KP * 2);
    u16* Wihhi = (u16*)alloc((size_t)3 * HH * HH * 2);
    u16* Whhhi = (u16*)alloc((size_t)3 * HH * HH * 2);
    u16* Wg1hi = (u16*)alloc((size_t)HH * HH * 2);
    u16* Wfcb  = (u16*)alloc((size_t)NPAD * HH * 2);

    hipMemsetAsync(msg, 0, (size_t)NN * HH * sizeof(float), stream);
    hipMemsetAsync(cnt, 0, (size_t)NN * sizeof(float), stream);

    // weight conversions (hi-only)
    k_cvt_wm<<<(HH * KP + 255) / 256, 256, 0, stream>>>(Wm, Wmhi);
    k_cvt_hi<<<(3 * HH * HH + 255) / 256, 256, 0, stream>>>(W_ih, Wihhi, 3 * HH * HH, 3 * HH * HH);
    k_cvt_hi<<<(3 * HH * HH + 255) / 256, 256, 0, stream>>>(W_hh, Whhhi, 3 * HH * HH, 3 * HH * HH);
    k_cvt_hi<<<(HH * HH + 255) / 256, 256, 0, stream>>>(Wg1, Wg1hi, HH * HH, HH * HH);
    k_cvt_hi<<<(NPAD * HH + 255) / 256, 256, 0, stream>>>(Wfc, Wfcb, ITEMS * HH, NPAD * HH);

    // 1. embedding gather -> X hi
    k_embed<<<NN / 4, 256, 0, stream>>>(category, sub_cat, element, brand, pid, price,
                                        ecat, esub, eel, ebr, eitem, Xhi);
    // 2. h = X @ Wm^T + bm (pair)
    k_mlp1<<<NN / 128, 256, 0, stream>>>(Xhi, Wmhi, bm, hhi, hlo);
    // 3. scatter (bf16 gather; mean fused into k_gru)
    k_scatter<<<EE / 16, 256, 0, stream>>>(hhi, edge, msg, cnt);
    // 4. fused GRU (updates pair in place)
    k_gru<<<NN / 32, 256, 0, stream>>>(msg, cnt, Wihhi, Whhhi, b_ih, b_hh, hhi, hlo);
    // 5. fused gate + softmax + pool -> pooled pair
    k_gatepool<<<NN / 128, 256, 0, stream>>>(hhi, hlo, Wg1hi, bg1, Wg2, phi, plo);
    // 6. out = pooled @ Wfc^T + bfc
    k_fc13<<<dim3(416), 256, 0, stream>>>(Wfcb, phi, plo, bfc, out);
}

// Round 17
// 371.693 us; speedup vs baseline: 1.5081x; 1.1393x over previous
//
#include <hip/hip_runtime.h>
#include <hip/hip_bf16.h>
#include <cstdint>
#include <cstddef>

#define NN 65536
#define EE 131072
#define GG 4096
#define HH 128
#define DD 64
#define KP 384        // padded input-feature K (321 -> 384)
#define ITEMS 50000
#define NPAD 50176    // 98 * 512

typedef __attribute__((ext_vector_type(8))) short bf16x8;
typedef __attribute__((ext_vector_type(4))) float f32x4;
typedef unsigned short u16;
typedef __attribute__((ext_vector_type(4))) unsigned short u16x4;

#define PINV(x) asm volatile("" : "+v"(x))

__device__ inline void split2(float x, u16* hi, u16* lo) {
    __hip_bfloat16 h = __float2bfloat16(x);
    float hf = __bfloat162float(h);
    __hip_bfloat16 l = __float2bfloat16(x - hf);
    *hi = *reinterpret_cast<u16*>(&h);
    *lo = *reinterpret_cast<u16*>(&l);
}
__device__ inline u16 hi_only(float x) {
    __hip_bfloat16 h = __float2bfloat16(x);
    return *reinterpret_cast<u16*>(&h);
}
__device__ inline float bf2f(u16 v) {
    unsigned int u = ((unsigned int)v) << 16;
    return *reinterpret_cast<float*>(&u);
}
// packed 2x bf16 atomic add (gfx940+ instruction, no-return form)
__device__ inline void atomic_pk_bf16(u16* addr, unsigned int data) {
    asm volatile("global_atomic_pk_add_bf16 %0, %1, off"
                 :: "v"(addr), "v"(data) : "memory");
}

// ---------------- mega-prep: embed + msg/cnt zero + all weight conversions ----------------
#define PREP_EMBED 16384   // NN/4
#define PREP_MSGZ  4096    // NN*HH*2 B / (256*16)
#define PREP_CNTZ  64      // NN*4 B / (256*16)
#define PREP_WM    192     // 128*384/256
#define PREP_WIH   192     // 3*128*128/256
#define PREP_WHH   192
#define PREP_WG1   64      // 128*128/256
#define PREP_WFC   25088   // NPAD*128/256
// grid = 16384+4096+64+192+192+192+64+25088 = 46272
__global__ void k_prep(const int* __restrict__ cat, const int* __restrict__ sub,
                       const int* __restrict__ el, const int* __restrict__ br,
                       const int* __restrict__ pid, const float* __restrict__ price,
                       const float* __restrict__ ecat, const float* __restrict__ esub,
                       const float* __restrict__ eel, const float* __restrict__ ebr,
                       const float* __restrict__ eitem,
                       const float* __restrict__ Wm, const float* __restrict__ W_ih,
                       const float* __restrict__ W_hh, const float* __restrict__ Wg1,
                       const float* __restrict__ Wfc,
                       u16* __restrict__ Xhi, u16* __restrict__ msgb,
                       float* __restrict__ cnt,
                       u16* __restrict__ Wmhi, u16* __restrict__ Wihhi,
                       u16* __restrict__ Whhhi, u16* __restrict__ Wg1hi,
                       u16* __restrict__ Wfcb) {
    int b = blockIdx.x;
    int tid = threadIdx.x;
    if (b < PREP_EMBED) {
        int n = b * 4 + (tid >> 6);
        int l = tid & 63;
        u16* xh = Xhi + (size_t)n * KP;
        if (l == 0) xh[0] = hi_only(price[n]);
        xh[1 + l]   = hi_only(ecat[(size_t)cat[n] * DD + l]);
        xh[65 + l]  = hi_only(esub[(size_t)sub[n] * DD + l]);
        xh[129 + l] = hi_only(eel [(size_t)el[n]  * DD + l]);
        xh[193 + l] = hi_only(ebr [(size_t)br[n]  * DD + l]);
        xh[257 + l] = hi_only(eitem[(size_t)pid[n]* DD + l]);
        if (l < 63) xh[321 + l] = 0;
        return;
    }
    b -= PREP_EMBED;
    if (b < PREP_MSGZ) {
        ((f32x4*)msgb)[(size_t)b * 256 + tid] = (f32x4){0.f, 0.f, 0.f, 0.f};
        return;
    }
    b -= PREP_MSGZ;
    if (b < PREP_CNTZ) {
        ((f32x4*)cnt)[(size_t)b * 256 + tid] = (f32x4){0.f, 0.f, 0.f, 0.f};
        return;
    }
    b -= PREP_CNTZ;
    if (b < PREP_WM) {
        int i = b * 256 + tid;
        int r = i / KP, c = i - r * KP;
        Wmhi[i] = (c < 321) ? hi_only(Wm[r * 321 + c]) : (u16)0;
        return;
    }
    b -= PREP_WM;
    if (b < PREP_WIH) { int i = b * 256 + tid; Wihhi[i] = hi_only(W_ih[i]); return; }
    b -= PREP_WIH;
    if (b < PREP_WHH) { int i = b * 256 + tid; Whhhi[i] = hi_only(W_hh[i]); return; }
    b -= PREP_WHH;
    if (b < PREP_WG1) { int i = b * 256 + tid; Wg1hi[i] = hi_only(Wg1[i]); return; }
    b -= PREP_WG1;
    {
        int i = b * 256 + tid;
        Wfcb[i] = (i < ITEMS * HH) ? hi_only(Wfc[i]) : (u16)0;
    }
}

// ---------------- h = X @ Wm^T + bm  (1-pass MFMA, emits hi/lo pair) ----------------
#define M1_STR 132
__launch_bounds__(256, 2)
__global__ void k_mlp1(const u16* __restrict__ Xhi, const u16* __restrict__ Whi,
                       const float* __restrict__ bm,
                       u16* __restrict__ hhi, u16* __restrict__ hlo) {
    __shared__ float ls[128 * M1_STR];
    int tid = threadIdx.x, w = tid >> 6, l = tid & 63;
    int lr = l & 15, lk = l >> 4;
    int m0 = blockIdx.x * 128;
    f32x4 acc[2][8];
    #pragma unroll
    for (int rt = 0; rt < 2; ++rt)
        #pragma unroll
        for (int ci = 0; ci < 8; ++ci) acc[rt][ci] = (f32x4){0.f, 0.f, 0.f, 0.f};

    for (int kc = 0; kc < 12; ++kc) {
        bf16x8 ah[2];
        #pragma unroll
        for (int rt = 0; rt < 2; ++rt) {
            size_t off = (size_t)(m0 + w * 32 + rt * 16 + lr) * KP + kc * 32 + lk * 8;
            ah[rt] = *(const bf16x8*)(Xhi + off);
        }
        #pragma unroll
        for (int ci = 0; ci < 8; ++ci) {
            size_t boff = (size_t)(ci * 16 + lr) * KP + kc * 32 + lk * 8;
            bf16x8 bh = *(const bf16x8*)(Whi + boff);
            #pragma unroll
            for (int rt = 0; rt < 2; ++rt)
                acc[rt][ci] = __builtin_amdgcn_mfma_f32_16x16x32_bf16(ah[rt], bh, acc[rt][ci], 0, 0, 0);
        }
    }
    #pragma unroll
    for (int rt = 0; rt < 2; ++rt)
        #pragma unroll
        for (int ci = 0; ci < 8; ++ci) {
            int col = ci * 16 + lr;
            float bv = bm[col];
            #pragma unroll
            for (int q = 0; q < 4; ++q)
                ls[(w * 32 + rt * 16 + lk * 4 + q) * M1_STR + col] = acc[rt][ci][q] + bv;
        }
    __syncthreads();
    int row = tid >> 1, cb = (tid & 1) * 64;
    u16* hh = hhi + (size_t)(m0 + row) * HH + cb;
    u16* hl = hlo + (size_t)(m0 + row) * HH + cb;
    #pragma unroll
    for (int i = 0; i < 64; i += 4) {
        float4 v = *(const float4*)&ls[row * M1_STR + cb + i];
        u16x4 vh, vl;
        split2(v.x, (u16*)&vh + 0, (u16*)&vl + 0);
        split2(v.y, (u16*)&vh + 1, (u16*)&vl + 1);
        split2(v.z, (u16*)&vh + 2, (u16*)&vl + 2);
        split2(v.w, (u16*)&vh + 3, (u16*)&vl + 3);
        *(u16x4*)(hh + i) = vh;
        *(u16x4*)(hl + i) = vl;
    }
}

// ---------------- edge scatter via packed-bf16 atomics ----------------
// lane l covers cols [2l, 2l+1]; one pk-atomic per lane, one wave per edge.
__global__ void k_scatter(const u16* __restrict__ hhi, const int* __restrict__ edge,
                          u16* __restrict__ msgb, float* __restrict__ cnt) {
    int w = threadIdx.x >> 6;
    int l = threadIdx.x & 63;
    int e0 = blockIdx.x * 16;
    #pragma unroll
    for (int it = 0; it < 4; ++it) {
        int e = e0 + it * 4 + w;
        int s = edge[e];
        int d = edge[EE + e];
        unsigned int pk = *(const unsigned int*)(hhi + (size_t)s * HH + 2 * l);
        atomic_pk_bf16(msgb + (size_t)d * HH + 2 * l, pk);
        if (l == 0) atomicAdd(&cnt[d], 1.0f);
    }
}

// ---------------- fused GRU: mean + both GEMMs (1-pass) + gates; h as pair ----------------
#define GRU_STR 136
__launch_bounds__(256, 2)
__global__ void k_gru(const u16* __restrict__ msgb, const float* __restrict__ cnt,
                      const u16* __restrict__ Wihh, const u16* __restrict__ Whhh,
                      const float* __restrict__ b_ih, const float* __restrict__ b_hh,
                      u16* __restrict__ hhi, u16* __restrict__ hlo) {
    __shared__ float ls[32 * GRU_STR];
    int tid = threadIdx.x, w = tid >> 6, l = tid & 63;
    int lr = l & 15, lk = l >> 4;
    int m0 = blockIdx.x * 32;
    f32x4 acc[6][2][2];
    #pragma unroll
    for (int g = 0; g < 6; ++g)
        #pragma unroll
        for (int ct = 0; ct < 2; ++ct)
            #pragma unroll
            for (int rt = 0; rt < 2; ++rt) acc[g][ct][rt] = (f32x4){0.f, 0.f, 0.f, 0.f};

    float cinv[2];
    const u16* mrowb[2];
    #pragma unroll
    for (int rt = 0; rt < 2; ++rt) {
        int row = m0 + rt * 16 + lr;
        cinv[rt] = 1.0f / fmaxf(cnt[row], 1.0f);
        mrowb[rt] = msgb + (size_t)row * HH + lk * 8;
    }

    for (int kc = 0; kc < 4; ++kc) {
        bf16x8 amh[2], ahh[2];
        #pragma unroll
        for (int rt = 0; rt < 2; ++rt) {
            bf16x8 mv = *(const bf16x8*)(mrowb[rt] + kc * 32);
            #pragma unroll
            for (int q = 0; q < 8; ++q)
                amh[rt][q] = (short)hi_only(bf2f((u16)mv[q]) * cinv[rt]);
            size_t off = (size_t)(m0 + rt * 16 + lr) * HH + kc * 32 + lk * 8;
            ahh[rt] = *(const bf16x8*)(hhi + off);
        }
        #pragma unroll
        for (int g = 0; g < 6; ++g) {
            const u16* WH = (g < 3) ? Wihh : Whhh;
            int gb = (g % 3) * HH;
            #pragma unroll
            for (int ct = 0; ct < 2; ++ct) {
                size_t boff = (size_t)(gb + w * 32 + ct * 16 + lr) * HH + kc * 32 + lk * 8;
                bf16x8 bh = *(const bf16x8*)(WH + boff);
                #pragma unroll
                for (int rt = 0; rt < 2; ++rt) {
                    bf16x8 ah = (g < 3) ? amh[rt] : ahh[rt];
                    acc[g][ct][rt] = __builtin_amdgcn_mfma_f32_16x16x32_bf16(ah, bh, acc[g][ct][rt], 0, 0, 0);
                }
            }
        }
    }
    #pragma unroll
    for (int ct = 0; ct < 2; ++ct) {
        int col = w * 32 + ct * 16 + lr;
        float bir = b_ih[col], biz = b_ih[HH + col], bin = b_ih[2 * HH + col];
        float bhr = b_hh[col], bhz = b_hh[HH + col], bhn = b_hh[2 * HH + col];
        #pragma unroll
        for (int rt = 0; rt < 2; ++rt)
            #pragma unroll
            for (int q = 0; q < 4; ++q) {
                int rl = rt * 16 + lk * 4 + q;
                size_t idx = (size_t)(m0 + rl) * HH + col;
                float gir = acc[0][ct][rt][q] + bir;
                float giz = acc[1][ct][rt][q] + biz;
                float gin = acc[2][ct][rt][q] + bin;
                float ghr = acc[3][ct][rt][q] + bhr;
                float ghz = acc[4][ct][rt][q] + bhz;
                float ghn = acc[5][ct][rt][q] + bhn;
                float hv = bf2f(hhi[idx]) + bf2f(hlo[idx]);
                float r = 1.f / (1.f + expf(-(gir + ghr)));
                float z = 1.f / (1.f + expf(-(giz + ghz)));
                float nn = tanhf(gin + r * ghn);
                ls[rl * GRU_STR + col] = (1.f - z) * nn + z * hv;
            }
    }
    __syncthreads();
    int row = tid >> 3, cb = (tid & 7) * 16;
    u16* hh = hhi + (size_t)(m0 + row) * HH + cb;
    u16* hl = hlo + (size_t)(m0 + row) * HH + cb;
    #pragma unroll
    for (int i = 0; i < 16; i += 4) {
        float4 v = *(const float4*)&ls[row * GRU_STR + cb + i];
        u16x4 vh, vl;
        split2(v.x, (u16*)&vh + 0, (u16*)&vl + 0);
        split2(v.y, (u16*)&vh + 1, (u16*)&vl + 1);
        split2(v.z, (u16*)&vh + 2, (u16*)&vl + 2);
        split2(v.w, (u16*)&vh + 3, (u16*)&vl + 3);
        *(u16x4*)(hh + i) = vh;
        *(u16x4*)(hl + i) = vl;
    }
}

// ---------------- fused gate + segment-softmax + pool + split ----------------
__launch_bounds__(256, 2)
__global__ void k_gatepool(const u16* __restrict__ hhi, const u16* __restrict__ hlo,
                           const u16* __restrict__ Ghi, const float* __restrict__ bg1,
                           const float* __restrict__ Wg2,
                           u16* __restrict__ phi, u16* __restrict__ plo) {
    __shared__ float sal[128];
    int tid = threadIdx.x, w = tid >> 6, l = tid & 63;
    int lr = l & 15, lk = l >> 4;
    int m0 = blockIdx.x * 128;
    f32x4 acc[2][8];
    #pragma unroll
    for (int rt = 0; rt < 2; ++rt)
        #pragma unroll
        for (int ci = 0; ci < 8; ++ci) acc[rt][ci] = (f32x4){0.f, 0.f, 0.f, 0.f};

    for (int kc = 0; kc < 4; ++kc) {
        bf16x8 ah[2];
        #pragma unroll
        for (int rt = 0; rt < 2; ++rt) {
            size_t off = (size_t)(m0 + w * 32 + rt * 16 + lr) * HH + kc * 32 + lk * 8;
            ah[rt] = *(const bf16x8*)(hhi + off);
        }
        #pragma unroll
        for (int ci = 0; ci < 8; ++ci) {
            size_t boff = (size_t)(ci * 16 + lr) * HH + kc * 32 + lk * 8;
            bf16x8 bh = *(const bf16x8*)(Ghi + boff);
            #pragma unroll
            for (int rt = 0; rt < 2; ++rt)
                acc[rt][ci] = __builtin_amdgcn_mfma_f32_16x16x32_bf16(ah[rt], bh, acc[rt][ci], 0, 0, 0);
        }
    }
    float part[2][4] = {};
    #pragma unroll
    for (int ci = 0; ci < 8; ++ci) {
        int col = ci * 16 + lr;
        float wv = Wg2[col], bb = bg1[col];
        #pragma unroll
        for (int rt = 0; rt < 2; ++rt)
            #pragma unroll
            for (int q = 0; q < 4; ++q)
                part[rt][q] += fmaxf(acc[rt][ci][q] + bb, 0.f) * wv;
    }
    #pragma unroll
    for (int rt = 0; rt < 2; ++rt)
        #pragma unroll
        for (int q = 0; q < 4; ++q) {
            float v = part[rt][q];
            v += __shfl_xor(v, 1);
            v += __shfl_xor(v, 2);
            v += __shfl_xor(v, 4);
            v += __shfl_xor(v, 8);
            part[rt][q] = v;
        }
    if (lr == 0) {
        #pragma unroll
        for (int rt = 0; rt < 2; ++rt)
            #pragma unroll
            for (int q = 0; q < 4; ++q)
                sal[w * 32 + rt * 16 + lk * 4 + q] = part[rt][q];
    }
    __syncthreads();

    int g2 = tid >> 5;
    int c = (tid & 31) * 4;
    int rb = g2 * 16;
    float gv[16];
    float mx = -1e30f;
    #pragma unroll
    for (int i = 0; i < 16; ++i) { gv[i] = sal[rb + i]; mx = fmaxf(mx, gv[i]); }
    float den = 0.f;
    #pragma unroll
    for (int i = 0; i < 16; ++i) { gv[i] = expf(gv[i] - mx); den += gv[i]; }
    float inv = 1.f / den;
    f32x4 a = (f32x4){0.f, 0.f, 0.f, 0.f};
    #pragma unroll
    for (int i = 0; i < 16; ++i) {
        size_t idx = (size_t)(m0 + rb + i) * HH + c;
        u16x4 xh = *(const u16x4*)(hhi + idx);
        u16x4 xl = *(const u16x4*)(hlo + idx);
        float wgt = gv[i] * inv;
        a[0] += wgt * (bf2f(xh.x) + bf2f(xl.x));
        a[1] += wgt * (bf2f(xh.y) + bf2f(xl.y));
        a[2] += wgt * (bf2f(xh.z) + bf2f(xl.z));
        a[3] += wgt * (bf2f(xh.w) + bf2f(xl.w));
    }
    size_t po = (size_t)(blockIdx.x * 8 + g2) * HH + c;
    u16x4 vh, vl;
    #pragma unroll
    for (int q = 0; q < 4; ++q) split2(a[q], (u16*)&vh + q, (u16*)&vl + q);
    *(u16x4*)(phi + po) = vh;
    *(u16x4*)(plo + po) = vl;
}

// ---------------- FC v13: XCD-coherent strips, bf16 Wfc, pinned regs ----------------
#define FC_STR 520
__launch_bounds__(256, 2)
__global__ void k_fc13(const u16* __restrict__ Wfcb,
                       const u16* __restrict__ phi, const u16* __restrict__ plo,
                       const float* __restrict__ bfc, float* __restrict__ out) {
    __shared__ float ls[2][16][FC_STR];
    int wg = blockIdx.x;
    int xcd = wg & 7;
    int r = wg >> 3;
    int strip = (r >> 2) * 8 + xcd;
    int phase = r & 3;
    if (strip >= 98) return;
    int tid = threadIdx.x, w = tid >> 6, l = tid & 63;
    int lr = l & 15, lk = l >> 4;
    int c0 = strip * 512;
    int mbase = phase * 1024;

    bf16x8 bh[8][4];
    float bias[8];
    #pragma unroll
    for (int ci = 0; ci < 8; ++ci) {
        int n = c0 + w * 128 + ci * 16 + lr;
        const u16* Wr = Wfcb + (size_t)n * HH + lk * 8;
        #pragma unroll
        for (int kc = 0; kc < 4; ++kc)
            bh[ci][kc] = *(const bf16x8*)(Wr + kc * 32);
        bias[ci] = (n < ITEMS) ? bfc[n] : 0.f;
    }
    #pragma unroll
    for (int ci = 0; ci < 8; ++ci)
        #pragma unroll
        for (int kc = 0; kc < 4; ++kc) PINV(bh[ci][kc]);

    bf16x8 a0h[4], a0l[4], a1h[4], a1l[4];
    auto LOADA = [&](int t, bf16x8* Ah, bf16x8* Al) {
        int m0 = mbase + t * 16;
        size_t aoff = (size_t)(m0 + lr) * HH + lk * 8;
        #pragma unroll
        for (int kc = 0; kc < 4; ++kc) {
            Ah[kc] = *(const bf16x8*)(phi + aoff + kc * 32);
            Al[kc] = *(const bf16x8*)(plo + aoff + kc * 32);
        }
    };
    auto COMP = [&](const bf16x8* Ah, const bf16x8* Al, int b) {
        #pragma unroll
        for (int ci = 0; ci < 8; ++ci) {
            f32x4 acc = (f32x4){0.f, 0.f, 0.f, 0.f};
            #pragma unroll
            for (int kc = 0; kc < 4; ++kc) {
                acc = __builtin_amdgcn_mfma_f32_16x16x32_bf16(Ah[kc], bh[ci][kc], acc, 0, 0, 0);
                acc = __builtin_amdgcn_mfma_f32_16x16x32_bf16(Al[kc], bh[ci][kc], acc, 0, 0, 0);
            }
            #pragma unroll
            for (int q = 0; q < 4; ++q)
                ls[b][lk * 4 + q][w * 128 + ci * 16 + lr] = acc[q] + bias[ci];
        }
    };
    auto FLUSH = [&](int t, int b) {
        int m0 = mbase + t * 16;
        #pragma unroll
        for (int p = 0; p < 4; ++p) {
            int row = w * 4 + p;
            #pragma unroll
            for (int s = 0; s < 2; ++s) {
                int c = s * 256 + l * 4;
                int gc = c0 + c;
                if (gc < ITEMS) {
                    f32x4 v = *(const f32x4*)&ls[b][row][c];
                    __builtin_nontemporal_store(v, (f32x4*)&out[(size_t)(m0 + row) * ITEMS + gc]);
                }
            }
        }
    };
    auto softbar = [&]() {
        asm volatile("s_waitcnt lgkmcnt(0)" ::: "memory");
        __builtin_amdgcn_s_barrier();
    };

    LOADA(0, a0h, a0l);
    LOADA(1, a1h, a1l);
    COMP(a0h, a0l, 0);
    softbar();
    for (int t = 1; t < 64; ++t) {
        if (t + 1 < 64) {
            if ((t + 1) & 1) LOADA(t + 1, a1h, a1l);
            else             LOADA(t + 1, a0h, a0l);
        }
        if (t & 1) COMP(a1h, a1l, 1);
        else       COMP(a0h, a0l, 0);
        FLUSH(t - 1, (t - 1) & 1);
        softbar();
    }
    FLUSH(63, 1);
}

extern "C" void kernel_launch(void* const* d_in, const int* in_sizes, int n_in,
                              void* d_out, int out_size, void* d_ws, size_t ws_size,
                              hipStream_t stream) {
    const int* category = (const int*)d_in[0];
    const int* sub_cat  = (const int*)d_in[1];
    const int* element  = (const int*)d_in[2];
    const int* brand    = (const int*)d_in[3];
    const int* pid      = (const int*)d_in[4];
    const float* price  = (const float*)d_in[5];
    const int* edge     = (const int*)d_in[6];
    const float* ecat   = (const float*)d_in[8];
    const float* esub   = (const float*)d_in[9];
    const float* eel    = (const float*)d_in[10];
    const float* ebr    = (const float*)d_in[11];
    const float* eitem  = (const float*)d_in[12];
    const float* Wm     = (const float*)d_in[13];
    const float* bm     = (const float*)d_in[14];
    const float* W_ih   = (const float*)d_in[15];
    const float* b_ih   = (const float*)d_in[16];
    const float* W_hh   = (const float*)d_in[17];
    const float* b_hh   = (const float*)d_in[18];
    const float* Wg1    = (const float*)d_in[19];
    const float* bg1    = (const float*)d_in[20];
    const float* Wg2    = (const float*)d_in[21];
    // d_in[22] = bg2 (cancels in softmax)
    const float* Wfc    = (const float*)d_in[23];
    const float* bfc    = (const float*)d_in[24];
    float* out = (float*)d_out;

    // ---- workspace carve-up (bytes), 256B-aligned regions ----
    char* p = (char*)d_ws;
    auto alloc = [&](size_t bytes) { char* r = p; p += (bytes + 255) & ~(size_t)255; return r; };
    u16* Xhi   = (u16*)alloc((size_t)NN * KP * 2);
    u16* hhi   = (u16*)alloc((size_t)NN * HH * 2);
    u16* hlo   = (u16*)alloc((size_t)NN * HH * 2);
    u16* msgb  = (u16*)alloc((size_t)NN * HH * 2);
    float* cnt = (float*)alloc((size_t)NN * 4);
    u16* phi   = (u16*)alloc((size_t)GG * HH * 2);
    u16* plo   = (u16*)alloc((size_t)GG * HH * 2);
    u16* Wmhi  = (u16*)alloc((size_t)HH * KP * 2);
    u16* Wihhi = (u16*)alloc((size_t)3 * HH * HH * 2);
    u16* Whhhi = (u16*)alloc((size_t)3 * HH * HH * 2);
    u16* Wg1hi = (u16*)alloc((size_t)HH * HH * 2);
    u16* Wfcb  = (u16*)alloc((size_t)NPAD * HH * 2);

    // 1. mega-prep: embed + zero msg/cnt + all weight conversions (one launch)
    const int prep_grid = PREP_EMBED + PREP_MSGZ + PREP_CNTZ + PREP_WM +
                          PREP_WIH + PREP_WHH + PREP_WG1 + PREP_WFC;
    k_prep<<<prep_grid, 256, 0, stream>>>(category, sub_cat, element, brand, pid, price,
                                          ecat, esub, eel, ebr, eitem,
                                          Wm, W_ih, W_hh, Wg1, Wfc,
                                          Xhi, msgb, cnt,
                                          Wmhi, Wihhi, Whhhi, Wg1hi, Wfcb);
    // 2. h = X @ Wm^T + bm (pair)
    k_mlp1<<<NN / 128, 256, 0, stream>>>(Xhi, Wmhi, bm, hhi, hlo);
    // 3. scatter (packed bf16 atomics; mean fused into k_gru)
    k_scatter<<<EE / 16, 256, 0, stream>>>(hhi, edge, msgb, cnt);
    // 4. fused GRU (updates pair in place)
    k_gru<<<NN / 32, 256, 0, stream>>>(msgb, cnt, Wihhi, Whhhi, b_ih, b_hh, hhi, hlo);
    // 5. fused gate + softmax + pool -> pooled pair
    k_gatepool<<<NN / 128, 256, 0, stream>>>(hhi, hlo, Wg1hi, bg1, Wg2, phi, plo);
    // 6. out = pooled @ Wfc^T + bfc
    k_fc13<<<dim3(416), 256, 0, stream>>>(Wfcb, phi, plo, bfc, out);
}